// Round 10
// baseline (779.669 us; speedup 1.0000x reference)
//
#include <hip/hip_runtime.h>
#include <hip/hip_fp16.h>

#define N_USERS 100000
#define M_ITEMS 50000
#define N_TOTAL (N_USERS + M_ITEMS)
#define D 64
#define NNZ 4000000
#define BATCH 4096

#define RPB 128                                   // rows per bucket (pow2)
#define BSHIFT 7
#define NBUCKETS ((N_TOTAL + RPB - 1) / RPB)      // 1172
#define BCAP 7680                                 // LDS edge capacity per bucket
#define PADB 384                                  // per-bucket slack (3*RPB) for row padding

#define TILE 8192                                 // edges per scatter block
#define SCAT_BLOCKS ((NNZ + TILE - 1) / TILE)     // 489
#define SCAT_THREADS 512
#define EPT (TILE / SCAT_THREADS)                 // 16 edges per thread
#define CPB 3                                     // buckets per thread in block scan

#define LS_THREADS 512
#define LS_EPT 16

// ---- half2 bit helpers ----
__device__ __forceinline__ __half2 u2h2(unsigned u) {
    union { unsigned u; __half2 h; } x; x.u = u; return x.h;
}
__device__ __forceinline__ unsigned h22u(__half2 h) {
    union { unsigned u; __half2 h; } x; x.h = h; return x.u;
}

// ---------------- init ----------------

// Concatenate + convert fp32 embeddings to packed f16 (4 dims per uint2).
__global__ void init_emb_kernel(const float4* __restrict__ ue,
                                const float4* __restrict__ ie,
                                uint2* __restrict__ emb) {
    size_t i = (size_t)blockIdx.x * blockDim.x + threadIdx.x;  // one float4 -> uint2
    const size_t nu4  = (size_t)N_USERS * D / 4;
    const size_t tot4 = (size_t)N_TOTAL * D / 4;
    if (i >= tot4) return;
    float4 f = (i < nu4) ? ue[i] : ie[i - nu4];
    __half2 h01 = __float22half2_rn(make_float2(f.x, f.y));
    __half2 h23 = __float22half2_rn(make_float2(f.z, f.w));
    emb[i] = make_uint2(h22u(h01), h22u(h23));
}

__global__ void init_acc_kernel(const int* __restrict__ users,
                                const int* __restrict__ items,
                                const float* __restrict__ ue,
                                const float* __restrict__ ie,
                                float* __restrict__ u_acc,
                                float* __restrict__ i_acc) {
    int gid = blockIdx.x * blockDim.x + threadIdx.x;  // 2*BATCH*D threads
    int d = gid & (D - 1);
    int b = gid >> 6;
    if (b < BATCH) {
        u_acc[(size_t)b * D + d] = ue[(size_t)users[b] * D + d];
    } else if (b < 2 * BATCH) {
        int bb = b - BATCH;
        i_acc[(size_t)bb * D + d] = ie[(size_t)items[bb] * D + d];
    }
}

// ---------------- CSR build: two-level bucketing ----------------

__global__ void bucket_hist_kernel(const int* __restrict__ rows,
                                   int* __restrict__ bucketcnt) {
    __shared__ int h[NBUCKETS];
    for (int i = threadIdx.x; i < NBUCKETS; i += blockDim.x) h[i] = 0;
    __syncthreads();
    int stride = gridDim.x * blockDim.x;
    for (int e = blockIdx.x * blockDim.x + threadIdx.x; e < NNZ; e += stride)
        atomicAdd(&h[rows[e] >> BSHIFT], 1);
    __syncthreads();
    for (int i = threadIdx.x; i < NBUCKETS; i += blockDim.x)
        if (h[i]) atomicAdd(&bucketcnt[i], h[i]);
}

__global__ void bucket_scan_kernel(const int* __restrict__ cnt,
                                   int* __restrict__ bucketoff,
                                   int* __restrict__ cursor) {
    __shared__ int sc[1024];
    int t = threadIdx.x;
    int i0 = t * 2, i1 = t * 2 + 1;
    int a = (i0 < NBUCKETS) ? cnt[i0] : 0;
    int b = (i1 < NBUCKETS) ? cnt[i1] : 0;
    sc[t] = a + b;
    __syncthreads();
    for (int o = 1; o < 1024; o <<= 1) {
        int v = (t >= o) ? sc[t - o] : 0;
        __syncthreads();
        sc[t] += v;
        __syncthreads();
    }
    int excl = (t == 0) ? 0 : sc[t - 1];
    if (i0 < NBUCKETS) { bucketoff[i0] = excl;     cursor[i0] = excl; }
    if (i1 < NBUCKETS) { bucketoff[i1] = excl + a; cursor[i1] = excl + a; }
    if (t == 0) bucketoff[NBUCKETS] = NNZ;
}

// Tile-aggregated scatter with LDS staging. Phase C also records each
// edge's global destination so phase D's stream-out is lane-parallel
// coalesced (consecutive LDS slots -> consecutive global addresses).
__global__ __launch_bounds__(SCAT_THREADS)
void bucket_scatter_kernel(const int* __restrict__ rows,
                           const int* __restrict__ cols,
                           const float* __restrict__ vals,
                           int* __restrict__ cursor,
                           int2* __restrict__ bucketed) {
    __shared__ int hist[NBUCKETS];        // counts, then global base per bucket
    __shared__ int loff[NBUCKETS + 1];    // local exclusive prefix
    __shared__ int partial[SCAT_THREADS];
    __shared__ int2 buf[TILE];            // 64 KB
    __shared__ int dst[TILE];             // 32 KB
    int t = threadIdx.x;
    size_t start = (size_t)blockIdx.x * TILE;
    int n = (int)(((size_t)NNZ - start < TILE) ? ((size_t)NNZ - start) : TILE);

    for (int i = t; i < NBUCKETS; i += SCAT_THREADS) hist[i] = 0;
    __syncthreads();
    // Phase A: histogram; atomicAdd's return IS the local rank.
    int rowv[EPT];
    int rank[EPT];
#pragma unroll
    for (int k = 0; k < EPT; ++k) {
        int i = t + k * SCAT_THREADS;
        if (i < n) {
            int r = rows[start + i];
            rowv[k] = r;
            rank[k] = atomicAdd(&hist[r >> BSHIFT], 1);
        }
    }
    __syncthreads();
    // Phase B1: block scan hist -> loff (exclusive)
    {
        int base = t * CPB;
        int s = 0;
#pragma unroll
        for (int j = 0; j < CPB; ++j) {
            int idx = base + j;
            if (idx < NBUCKETS) s += hist[idx];
        }
        partial[t] = s;
        __syncthreads();
        for (int o = 1; o < SCAT_THREADS; o <<= 1) {
            int v = (t >= o) ? partial[t - o] : 0;
            __syncthreads();
            partial[t] += v;
            __syncthreads();
        }
        int excl = (t == 0) ? 0 : partial[t - 1];
#pragma unroll
        for (int j = 0; j < CPB; ++j) {
            int idx = base + j;
            if (idx < NBUCKETS) { loff[idx] = excl; excl += hist[idx]; }
        }
        if (t == 0) loff[NBUCKETS] = n;
    }
    __syncthreads();
    // Phase B2: one global reservation per touched bucket; hist becomes gbase.
    for (int i = t; i < NBUCKETS; i += SCAT_THREADS) {
        int c = loff[i + 1] - loff[i];
        hist[i] = c ? atomicAdd(&cursor[i], c) : 0;
    }
    __syncthreads();
    // Phase C: place edges bucket-sorted in LDS; record global dest per slot.
#pragma unroll
    for (int k = 0; k < EPT; ++k) {
        int i = t + k * SCAT_THREADS;
        if (i < n) {
            int r = rowv[k];
            int bkt = r >> BSHIFT;
            int slot = loff[bkt] + rank[k];
            buf[slot] = make_int2(((r & (RPB - 1)) << 18) | cols[start + i],
                                  __float_as_int(vals[start + i]));
            dst[slot] = hist[bkt] + rank[k];
        }
    }
    __syncthreads();
    // Phase D: lane-parallel coalesced stream-out.
    for (int i = t; i < n; i += SCAT_THREADS)
        bucketed[dst[i]] = buf[i];
}

// Per-bucket counting sort in LDS. Rows padded to a multiple of 4 edges
// (zero-val edges); bucket segment slack-filled so row_start[r+1] is always
// a valid end. Output edge: x = col byte offset (col*128), y = half2(v,v).
__global__ __launch_bounds__(LS_THREADS)
void local_sort_kernel(const int* __restrict__ bucketoff,
                       const int2* __restrict__ bucketed,
                       int* __restrict__ row_start,
                       int2* __restrict__ edges) {
    __shared__ int hist[RPB];
    __shared__ int sc[RPB];
    __shared__ int2 buf[BCAP];
    int b = blockIdx.x;
    int t = threadIdx.x;
    int s = bucketoff[b], e = bucketoff[b + 1], n = e - s;
    int cap = n + PADB;                 // <= ~4100 < BCAP

    for (int i = t; i < cap; i += LS_THREADS) buf[i] = make_int2(0, 0);
    if (t < RPB) hist[t] = 0;
    __syncthreads();
    int rl[LS_EPT], rank[LS_EPT];
    int2 pay[LS_EPT];
#pragma unroll
    for (int k = 0; k < LS_EPT; ++k) {
        int i = t + k * LS_THREADS;
        if (i < n) {
            int2 ev = bucketed[s + i];
            rl[k] = (int)((unsigned)ev.x >> 18);
            float v = __int_as_float(ev.y);
            unsigned hv = (unsigned)__half_as_ushort(__float2half(v));
            pay[k] = make_int2((ev.x & 0x3FFFF) << 7, (int)(hv | (hv << 16)));
            rank[k] = atomicAdd(&hist[rl[k]], 1);
        }
    }
    __syncthreads();
    if (t < RPB) sc[t] = (hist[t] + 3) & ~3;   // padded degree
    __syncthreads();
    for (int o = 1; o < RPB; o <<= 1) {
        int v = (t < RPB && t >= o) ? sc[t - o] : 0;
        __syncthreads();
        if (t < RPB) sc[t] += v;
        __syncthreads();
    }
    int pbase = s + b * PADB;
    if (t < RPB) {
        int excl = (t == 0) ? 0 : sc[t - 1];
        int gr = b * RPB + t;
        if (gr < N_TOTAL) row_start[gr] = pbase + excl;
    }
    if (b == 0 && t == 0) row_start[N_TOTAL] = NNZ + NBUCKETS * PADB;
    __syncthreads();
#pragma unroll
    for (int k = 0; k < LS_EPT; ++k) {
        int i = t + k * LS_THREADS;
        if (i < n) {
            int excl = (rl[k] == 0) ? 0 : sc[rl[k] - 1];
            buf[excl + rank[k]] = pay[k];
        }
    }
    __syncthreads();
    for (int i = t; i < cap; i += LS_THREADS) edges[pbase + i] = buf[i];
}

// ---------------- f16 CSR SpMM, quarter-split, packed fma ----------------
// One wave per row (rows padded to 4k edges). quad = lane>>4 handles edges
// 4t+quad via a same-address broadcast load; ui = lane&15 covers dims
// 4ui..4ui+3 via one uint2 load (16 lanes x 8 B = 128 B/edge).
__global__ void spmm_csr_kernel(const int* __restrict__ row_start,
                                const int2* __restrict__ edges,   // x=col*128, y=half2(v,v)
                                const char* __restrict__ emb_in,  // f16 rows, 128 B
                                uint2* __restrict__ emb_out) {
    int wave = (blockIdx.x * blockDim.x + threadIdx.x) >> 6;
    int lane = threadIdx.x & 63;
    if (wave >= N_TOTAL) return;
    int quad = lane >> 4;
    int ui   = lane & 15;
    int s = row_start[wave];
    int e = row_start[wave + 1];
    int cnt = (e - s) >> 2;
    const int2* ep = edges + s + quad;
    int uioff = ui << 3;
    __half2 a01 = u2h2(0u), a23 = u2h2(0u);
    for (int t = 0; t < cnt; ++t) {
        int2 ev = ep[4 * t];
        uint2 p = *(const uint2*)(emb_in + ev.x + uioff);
        __half2 m2 = u2h2((unsigned)ev.y);
        a01 = __hfma2(m2, u2h2(p.x), a01);
        a23 = __hfma2(m2, u2h2(p.y), a23);
    }
    a01 = __hadd2(a01, u2h2(__shfl_xor(h22u(a01), 16, 64)));
    a23 = __hadd2(a23, u2h2(__shfl_xor(h22u(a23), 16, 64)));
    a01 = __hadd2(a01, u2h2(__shfl_xor(h22u(a01), 32, 64)));
    a23 = __hadd2(a23, u2h2(__shfl_xor(h22u(a23), 32, 64)));
    if (quad == 0)
        emb_out[(size_t)wave * 16 + ui] = make_uint2(h22u(a01), h22u(a23));
}

// Layer-3: segment sums ONLY for the 8192 batch rows, added into fp32 accs.
__global__ void layer3_kernel(const int* __restrict__ users,
                              const int* __restrict__ items,
                              const int* __restrict__ row_start,
                              const int2* __restrict__ edges,
                              const char* __restrict__ emb_in,  // f16 rows
                              float* __restrict__ u_acc,
                              float* __restrict__ i_acc) {
    int wave = (blockIdx.x * blockDim.x + threadIdx.x) >> 6;
    int lane = threadIdx.x & 63;
    if (wave >= 2 * BATCH) return;
    int quad = lane >> 4;
    int ui   = lane & 15;
    int row;
    float* dstp;
    if (wave < BATCH) {
        row = users[wave];
        dstp = &u_acc[(size_t)wave * D];
    } else {
        int bb = wave - BATCH;
        row = N_USERS + items[bb];
        dstp = &i_acc[(size_t)bb * D];
    }
    int s = row_start[row];
    int e = row_start[row + 1];
    int cnt = (e - s) >> 2;
    const int2* ep = edges + s + quad;
    int uioff = ui << 3;
    __half2 a01 = u2h2(0u), a23 = u2h2(0u);
    for (int t = 0; t < cnt; ++t) {
        int2 ev = ep[4 * t];
        uint2 p = *(const uint2*)(emb_in + ev.x + uioff);
        __half2 m2 = u2h2((unsigned)ev.y);
        a01 = __hfma2(m2, u2h2(p.x), a01);
        a23 = __hfma2(m2, u2h2(p.y), a23);
    }
    a01 = __hadd2(a01, u2h2(__shfl_xor(h22u(a01), 16, 64)));
    a23 = __hadd2(a23, u2h2(__shfl_xor(h22u(a23), 16, 64)));
    a01 = __hadd2(a01, u2h2(__shfl_xor(h22u(a01), 32, 64)));
    a23 = __hadd2(a23, u2h2(__shfl_xor(h22u(a23), 32, 64)));
    if (quad == 0) {
        float2 f01 = __half22float2(a01);
        float2 f23 = __half22float2(a23);
        dstp[4 * ui + 0] += f01.x;
        dstp[4 * ui + 1] += f01.y;
        dstp[4 * ui + 2] += f23.x;
        dstp[4 * ui + 3] += f23.y;
    }
}

// After layers 1,2: pull f16 emb rows at batch indices into fp32 accs.
__global__ void gather_acc_kernel(const int* __restrict__ users,
                                  const int* __restrict__ items,
                                  const __half2* __restrict__ emb,  // 32 half2/row
                                  float* __restrict__ u_acc,
                                  float* __restrict__ i_acc) {
    int gid = blockIdx.x * blockDim.x + threadIdx.x;  // 2*BATCH*32 threads
    int ui = gid & 31;
    int b  = gid >> 5;
    if (b < BATCH) {
        float2 f = __half22float2(emb[(size_t)users[b] * 32 + ui]);
        u_acc[(size_t)b * D + 2 * ui]     += f.x;
        u_acc[(size_t)b * D + 2 * ui + 1] += f.y;
    } else if (b < 2 * BATCH) {
        int bb = b - BATCH;
        float2 f = __half22float2(emb[((size_t)(N_USERS + items[bb])) * 32 + ui]);
        i_acc[(size_t)bb * D + 2 * ui]     += f.x;
        i_acc[(size_t)bb * D + 2 * ui + 1] += f.y;
    }
}

__global__ void final_dot_kernel(const float* __restrict__ u_acc,
                                 const float* __restrict__ i_acc,
                                 float* __restrict__ out) {
    int gid = blockIdx.x * blockDim.x + threadIdx.x;
    int b = gid >> 6;
    int lane = gid & 63;
    if (b >= BATCH) return;
    float p = u_acc[(size_t)b * D + lane] * i_acc[(size_t)b * D + lane];
#pragma unroll
    for (int o = 32; o; o >>= 1) p += __shfl_xor(p, o, 64);
    if (lane == 0) out[b] = p * (1.0f / 16.0f);
}

// ---------------- launch ----------------

extern "C" void kernel_launch(void* const* d_in, const int* in_sizes, int n_in,
                              void* d_out, int out_size, void* d_ws, size_t ws_size,
                              hipStream_t stream) {
    const int*   users = (const int*)d_in[0];
    const int*   items = (const int*)d_in[1];
    const float* ue    = (const float*)d_in[2];
    const float* ie    = (const float*)d_in[3];
    const int*   rows  = (const int*)d_in[4];
    const int*   cols  = (const int*)d_in[5];
    const float* vals  = (const float*)d_in[6];
    float*       out   = (float*)d_out;

    char* ws = (char*)d_ws;
    size_t off = 0;
    auto alloc = [&](size_t bytes) {
        void* p = ws + off;
        off += (bytes + 255) & ~(size_t)255;
        return p;
    };
    const size_t NBH = (size_t)N_TOTAL * D * sizeof(unsigned short);  // 19.2 MB f16
    const size_t NEDGE = (size_t)NNZ + (size_t)NBUCKETS * PADB;       // padded edges
    char*  embA      = (char*)alloc(NBH);
    char*  embB      = (char*)alloc(NBH);
    float* u_acc     = (float*)alloc((size_t)BATCH * D * sizeof(float));
    float* i_acc     = (float*)alloc((size_t)BATCH * D * sizeof(float));
    int*   row_start = (int*)alloc(((size_t)N_TOTAL + 1) * sizeof(int));
    int*   bucketcnt = (int*)alloc((size_t)NBUCKETS * sizeof(int));
    int*   bucketoff = (int*)alloc(((size_t)NBUCKETS + 1) * sizeof(int));
    int*   cursor    = (int*)alloc((size_t)NBUCKETS * sizeof(int));
    int2*  edges     = (int2*)alloc(NEDGE * sizeof(int2));
    int2*  bucketed  = (int2*)alloc((size_t)NNZ * sizeof(int2));

    // init
    {
        size_t tot4 = (size_t)N_TOTAL * D / 4;
        init_emb_kernel<<<(unsigned)((tot4 + 255) / 256), 256, 0, stream>>>(
            (const float4*)ue, (const float4*)ie, (uint2*)embA);
        init_acc_kernel<<<(2 * BATCH * D + 255) / 256, 256, 0, stream>>>(
            users, items, ue, ie, u_acc, i_acc);
    }

    // CSR build (two-level bucketing, LDS-staged coalesced scatter)
    hipMemsetAsync(bucketcnt, 0, (size_t)NBUCKETS * sizeof(int), stream);
    bucket_hist_kernel<<<512, 256, 0, stream>>>(rows, bucketcnt);
    bucket_scan_kernel<<<1, 1024, 0, stream>>>(bucketcnt, bucketoff, cursor);
    bucket_scatter_kernel<<<SCAT_BLOCKS, SCAT_THREADS, 0, stream>>>(
        rows, cols, vals, cursor, bucketed);
    local_sort_kernel<<<NBUCKETS, LS_THREADS, 0, stream>>>(
        bucketoff, bucketed, row_start, edges);

    // Layer 1: embA -> embB
    spmm_csr_kernel<<<(N_TOTAL * 64 + 255) / 256, 256, 0, stream>>>(
        row_start, edges, embA, (uint2*)embB);
    gather_acc_kernel<<<(2 * BATCH * 32 + 255) / 256, 256, 0, stream>>>(
        users, items, (const __half2*)embB, u_acc, i_acc);

    // Layer 2: embB -> embA
    spmm_csr_kernel<<<(N_TOTAL * 64 + 255) / 256, 256, 0, stream>>>(
        row_start, edges, embB, (uint2*)embA);
    gather_acc_kernel<<<(2 * BATCH * 32 + 255) / 256, 256, 0, stream>>>(
        users, items, (const __half2*)embA, u_acc, i_acc);

    // Layer 3: only the 8192 batch rows, straight into accs
    layer3_kernel<<<(2 * BATCH * 64 + 255) / 256, 256, 0, stream>>>(
        users, items, row_start, edges, embA, u_acc, i_acc);

    final_dot_kernel<<<(BATCH * 64 + 255) / 256, 256, 0, stream>>>(u_acc, i_acc, out);
}

// Round 11
// 607.972 us; speedup vs baseline: 1.2824x; 1.2824x over previous
//
#include <hip/hip_runtime.h>
#include <hip/hip_fp16.h>

#define N_USERS 100000
#define M_ITEMS 50000
#define N_TOTAL (N_USERS + M_ITEMS)
#define D 64
#define NNZ 4000000
#define BATCH 4096

#define RPB 128                                   // rows per bucket (pow2)
#define BSHIFT 7
#define NBUCKETS ((N_TOTAL + RPB - 1) / RPB)      // 1172
#define BCAP 7680                                 // LDS edge capacity per bucket
#define PADB 384                                  // per-bucket slack (3*RPB) for row padding

#define TILE 8192                                 // edges per scatter block
#define SCAT_BLOCKS ((NNZ + TILE - 1) / TILE)     // 489
#define SCAT_THREADS 512
#define EPT (TILE / SCAT_THREADS)                 // 16 edges per thread
#define CPB 3                                     // buckets per thread in block scan

#define LS_THREADS 512
#define LS_EPT 16

// ---- half2 bit helpers ----
__device__ __forceinline__ __half2 u2h2(unsigned u) {
    union { unsigned u; __half2 h; } x; x.u = u; return x.h;
}
__device__ __forceinline__ unsigned h22u(__half2 h) {
    union { unsigned u; __half2 h; } x; x.h = h; return x.u;
}

// ---------------- init ----------------

// Concatenate + convert fp32 embeddings to packed f16 (4 dims per uint2).
__global__ void init_emb_kernel(const float4* __restrict__ ue,
                                const float4* __restrict__ ie,
                                uint2* __restrict__ emb) {
    size_t i = (size_t)blockIdx.x * blockDim.x + threadIdx.x;  // one float4 -> uint2
    const size_t nu4  = (size_t)N_USERS * D / 4;
    const size_t tot4 = (size_t)N_TOTAL * D / 4;
    if (i >= tot4) return;
    float4 f = (i < nu4) ? ue[i] : ie[i - nu4];
    __half2 h01 = __float22half2_rn(make_float2(f.x, f.y));
    __half2 h23 = __float22half2_rn(make_float2(f.z, f.w));
    emb[i] = make_uint2(h22u(h01), h22u(h23));
}

__global__ void init_acc_kernel(const int* __restrict__ users,
                                const int* __restrict__ items,
                                const float* __restrict__ ue,
                                const float* __restrict__ ie,
                                float* __restrict__ u_acc,
                                float* __restrict__ i_acc) {
    int gid = blockIdx.x * blockDim.x + threadIdx.x;  // 2*BATCH*D threads
    int d = gid & (D - 1);
    int b = gid >> 6;
    if (b < BATCH) {
        u_acc[(size_t)b * D + d] = ue[(size_t)users[b] * D + d];
    } else if (b < 2 * BATCH) {
        int bb = b - BATCH;
        i_acc[(size_t)bb * D + d] = ie[(size_t)items[bb] * D + d];
    }
}

// ---------------- CSR build: two-level bucketing ----------------

__global__ void bucket_hist_kernel(const int* __restrict__ rows,
                                   int* __restrict__ bucketcnt) {
    __shared__ int h[NBUCKETS];
    for (int i = threadIdx.x; i < NBUCKETS; i += blockDim.x) h[i] = 0;
    __syncthreads();
    int stride = gridDim.x * blockDim.x;
    for (int e = blockIdx.x * blockDim.x + threadIdx.x; e < NNZ; e += stride)
        atomicAdd(&h[rows[e] >> BSHIFT], 1);
    __syncthreads();
    for (int i = threadIdx.x; i < NBUCKETS; i += blockDim.x)
        if (h[i]) atomicAdd(&bucketcnt[i], h[i]);
}

__global__ void bucket_scan_kernel(const int* __restrict__ cnt,
                                   int* __restrict__ bucketoff,
                                   int* __restrict__ cursor) {
    __shared__ int sc[1024];
    int t = threadIdx.x;
    int i0 = t * 2, i1 = t * 2 + 1;
    int a = (i0 < NBUCKETS) ? cnt[i0] : 0;
    int b = (i1 < NBUCKETS) ? cnt[i1] : 0;
    sc[t] = a + b;
    __syncthreads();
    for (int o = 1; o < 1024; o <<= 1) {
        int v = (t >= o) ? sc[t - o] : 0;
        __syncthreads();
        sc[t] += v;
        __syncthreads();
    }
    int excl = (t == 0) ? 0 : sc[t - 1];
    if (i0 < NBUCKETS) { bucketoff[i0] = excl;     cursor[i0] = excl; }
    if (i1 < NBUCKETS) { bucketoff[i1] = excl + a; cursor[i1] = excl + a; }
    if (t == 0) bucketoff[NBUCKETS] = NNZ;
}

// Tile-aggregated scatter with LDS staging; lane-parallel coalesced stream-out.
__global__ __launch_bounds__(SCAT_THREADS)
void bucket_scatter_kernel(const int* __restrict__ rows,
                           const int* __restrict__ cols,
                           const float* __restrict__ vals,
                           int* __restrict__ cursor,
                           int2* __restrict__ bucketed) {
    __shared__ int hist[NBUCKETS];        // counts, then global base per bucket
    __shared__ int loff[NBUCKETS + 1];    // local exclusive prefix
    __shared__ int partial[SCAT_THREADS];
    __shared__ int2 buf[TILE];            // 64 KB
    __shared__ int dst[TILE];             // 32 KB
    int t = threadIdx.x;
    size_t start = (size_t)blockIdx.x * TILE;
    int n = (int)(((size_t)NNZ - start < TILE) ? ((size_t)NNZ - start) : TILE);

    for (int i = t; i < NBUCKETS; i += SCAT_THREADS) hist[i] = 0;
    __syncthreads();
    // Phase A: histogram; atomicAdd's return IS the local rank.
    int rowv[EPT];
    int rank[EPT];
#pragma unroll
    for (int k = 0; k < EPT; ++k) {
        int i = t + k * SCAT_THREADS;
        if (i < n) {
            int r = rows[start + i];
            rowv[k] = r;
            rank[k] = atomicAdd(&hist[r >> BSHIFT], 1);
        }
    }
    __syncthreads();
    // Phase B1: block scan hist -> loff (exclusive)
    {
        int base = t * CPB;
        int s = 0;
#pragma unroll
        for (int j = 0; j < CPB; ++j) {
            int idx = base + j;
            if (idx < NBUCKETS) s += hist[idx];
        }
        partial[t] = s;
        __syncthreads();
        for (int o = 1; o < SCAT_THREADS; o <<= 1) {
            int v = (t >= o) ? partial[t - o] : 0;
            __syncthreads();
            partial[t] += v;
            __syncthreads();
        }
        int excl = (t == 0) ? 0 : partial[t - 1];
#pragma unroll
        for (int j = 0; j < CPB; ++j) {
            int idx = base + j;
            if (idx < NBUCKETS) { loff[idx] = excl; excl += hist[idx]; }
        }
        if (t == 0) loff[NBUCKETS] = n;
    }
    __syncthreads();
    // Phase B2: one global reservation per touched bucket; hist becomes gbase.
    for (int i = t; i < NBUCKETS; i += SCAT_THREADS) {
        int c = loff[i + 1] - loff[i];
        hist[i] = c ? atomicAdd(&cursor[i], c) : 0;
    }
    __syncthreads();
    // Phase C: place edges bucket-sorted in LDS; record global dest per slot.
#pragma unroll
    for (int k = 0; k < EPT; ++k) {
        int i = t + k * SCAT_THREADS;
        if (i < n) {
            int r = rowv[k];
            int bkt = r >> BSHIFT;
            int slot = loff[bkt] + rank[k];
            buf[slot] = make_int2(((r & (RPB - 1)) << 18) | cols[start + i],
                                  __float_as_int(vals[start + i]));
            dst[slot] = hist[bkt] + rank[k];
        }
    }
    __syncthreads();
    // Phase D: lane-parallel coalesced stream-out.
    for (int i = t; i < n; i += SCAT_THREADS)
        bucketed[dst[i]] = buf[i];
}

// Per-bucket counting sort in LDS. Rows padded to a multiple of 4 edges
// (zero-val edges); bucket segment slack-filled. Output edge:
// x = col byte offset (col*128), y = half2(v,v).
__global__ __launch_bounds__(LS_THREADS)
void local_sort_kernel(const int* __restrict__ bucketoff,
                       const int2* __restrict__ bucketed,
                       int* __restrict__ row_start,
                       int2* __restrict__ edges) {
    __shared__ int hist[RPB];
    __shared__ int sc[RPB];
    __shared__ int2 buf[BCAP];
    int b = blockIdx.x;
    int t = threadIdx.x;
    int s = bucketoff[b], e = bucketoff[b + 1], n = e - s;
    int cap = n + PADB;                 // <= ~4100 < BCAP

    for (int i = t; i < cap; i += LS_THREADS) buf[i] = make_int2(0, 0);
    if (t < RPB) hist[t] = 0;
    __syncthreads();
    int rl[LS_EPT], rank[LS_EPT];
    int2 pay[LS_EPT];
#pragma unroll
    for (int k = 0; k < LS_EPT; ++k) {
        int i = t + k * LS_THREADS;
        if (i < n) {
            int2 ev = bucketed[s + i];
            rl[k] = (int)((unsigned)ev.x >> 18);
            float v = __int_as_float(ev.y);
            unsigned hv = (unsigned)__half_as_ushort(__float2half(v));
            pay[k] = make_int2((ev.x & 0x3FFFF) << 7, (int)(hv | (hv << 16)));
            rank[k] = atomicAdd(&hist[rl[k]], 1);
        }
    }
    __syncthreads();
    if (t < RPB) sc[t] = (hist[t] + 3) & ~3;   // padded degree
    __syncthreads();
    for (int o = 1; o < RPB; o <<= 1) {
        int v = (t < RPB && t >= o) ? sc[t - o] : 0;
        __syncthreads();
        if (t < RPB) sc[t] += v;
        __syncthreads();
    }
    int pbase = s + b * PADB;
    if (t < RPB) {
        int excl = (t == 0) ? 0 : sc[t - 1];
        int gr = b * RPB + t;
        if (gr < N_TOTAL) row_start[gr] = pbase + excl;
    }
    if (b == 0 && t == 0) row_start[N_TOTAL] = NNZ + NBUCKETS * PADB;
    __syncthreads();
#pragma unroll
    for (int k = 0; k < LS_EPT; ++k) {
        int i = t + k * LS_THREADS;
        if (i < n) {
            int excl = (rl[k] == 0) ? 0 : sc[rl[k] - 1];
            buf[excl + rank[k]] = pay[k];
        }
    }
    __syncthreads();
    for (int i = t; i < cap; i += LS_THREADS) edges[pbase + i] = buf[i];
}

// ---------------- f16 CSR SpMM, quarter-split, shfl-broadcast ----------------
// One wave per row (row lengths multiple of 4). Each lane loads one edge of
// the 64-chunk (coalesced, high MLP); quad = lane>>4 consumes edges 4t+quad
// via shfl broadcast; ui = lane&15 covers dims 4ui..4ui+3 via one uint2 load.
__global__ void spmm_csr_kernel(const int* __restrict__ row_start,
                                const int2* __restrict__ edges,   // x=col*128, y=half2(v,v)
                                const char* __restrict__ emb_in,  // f16 rows, 128 B
                                uint2* __restrict__ emb_out) {
    int wave = (blockIdx.x * blockDim.x + threadIdx.x) >> 6;
    int lane = threadIdx.x & 63;
    if (wave >= N_TOTAL) return;
    int quad = lane >> 4;
    int ui   = lane & 15;
    int uioff = ui << 3;
    int s = row_start[wave];
    int e = row_start[wave + 1];      // e - s is a multiple of 4
    __half2 a01 = u2h2(0u), a23 = u2h2(0u);
    for (int base = s; base < e; base += 64) {
        int n = e - base; if (n > 64) n = 64;    // multiple of 4
        int c = 0, vb = 0;
        if (base + lane < e) {
            int2 ev = edges[base + lane];
            c = ev.x; vb = ev.y;
        }
        int tmax = n >> 2;
        for (int t = 0; t < tmax; ++t) {
            int j = 4 * t + quad;                // j < n always (n % 4 == 0)
            int cj = __shfl(c, j, 64);
            int mj = __shfl(vb, j, 64);
            uint2 p = *(const uint2*)(emb_in + cj + uioff);
            __half2 m2 = u2h2((unsigned)mj);
            a01 = __hfma2(m2, u2h2(p.x), a01);
            a23 = __hfma2(m2, u2h2(p.y), a23);
        }
    }
    a01 = __hadd2(a01, u2h2(__shfl_xor(h22u(a01), 16, 64)));
    a23 = __hadd2(a23, u2h2(__shfl_xor(h22u(a23), 16, 64)));
    a01 = __hadd2(a01, u2h2(__shfl_xor(h22u(a01), 32, 64)));
    a23 = __hadd2(a23, u2h2(__shfl_xor(h22u(a23), 32, 64)));
    if (quad == 0)
        emb_out[(size_t)wave * 16 + ui] = make_uint2(h22u(a01), h22u(a23));
}

// Layer-3: segment sums ONLY for the 8192 batch rows, added into fp32 accs.
__global__ void layer3_kernel(const int* __restrict__ users,
                              const int* __restrict__ items,
                              const int* __restrict__ row_start,
                              const int2* __restrict__ edges,
                              const char* __restrict__ emb_in,  // f16 rows
                              float* __restrict__ u_acc,
                              float* __restrict__ i_acc) {
    int wave = (blockIdx.x * blockDim.x + threadIdx.x) >> 6;
    int lane = threadIdx.x & 63;
    if (wave >= 2 * BATCH) return;
    int quad = lane >> 4;
    int ui   = lane & 15;
    int uioff = ui << 3;
    int row;
    float* dstp;
    if (wave < BATCH) {
        row = users[wave];
        dstp = &u_acc[(size_t)wave * D];
    } else {
        int bb = wave - BATCH;
        row = N_USERS + items[bb];
        dstp = &i_acc[(size_t)bb * D];
    }
    int s = row_start[row];
    int e = row_start[row + 1];
    __half2 a01 = u2h2(0u), a23 = u2h2(0u);
    for (int base = s; base < e; base += 64) {
        int n = e - base; if (n > 64) n = 64;
        int c = 0, vb = 0;
        if (base + lane < e) {
            int2 ev = edges[base + lane];
            c = ev.x; vb = ev.y;
        }
        int tmax = n >> 2;
        for (int t = 0; t < tmax; ++t) {
            int j = 4 * t + quad;
            int cj = __shfl(c, j, 64);
            int mj = __shfl(vb, j, 64);
            uint2 p = *(const uint2*)(emb_in + cj + uioff);
            __half2 m2 = u2h2((unsigned)mj);
            a01 = __hfma2(m2, u2h2(p.x), a01);
            a23 = __hfma2(m2, u2h2(p.y), a23);
        }
    }
    a01 = __hadd2(a01, u2h2(__shfl_xor(h22u(a01), 16, 64)));
    a23 = __hadd2(a23, u2h2(__shfl_xor(h22u(a23), 16, 64)));
    a01 = __hadd2(a01, u2h2(__shfl_xor(h22u(a01), 32, 64)));
    a23 = __hadd2(a23, u2h2(__shfl_xor(h22u(a23), 32, 64)));
    if (quad == 0) {
        float2 f01 = __half22float2(a01);
        float2 f23 = __half22float2(a23);
        dstp[4 * ui + 0] += f01.x;
        dstp[4 * ui + 1] += f01.y;
        dstp[4 * ui + 2] += f23.x;
        dstp[4 * ui + 3] += f23.y;
    }
}

// After layers 1,2: pull f16 emb rows at batch indices into fp32 accs.
__global__ void gather_acc_kernel(const int* __restrict__ users,
                                  const int* __restrict__ items,
                                  const __half2* __restrict__ emb,  // 32 half2/row
                                  float* __restrict__ u_acc,
                                  float* __restrict__ i_acc) {
    int gid = blockIdx.x * blockDim.x + threadIdx.x;  // 2*BATCH*32 threads
    int ui = gid & 31;
    int b  = gid >> 5;
    if (b < BATCH) {
        float2 f = __half22float2(emb[(size_t)users[b] * 32 + ui]);
        u_acc[(size_t)b * D + 2 * ui]     += f.x;
        u_acc[(size_t)b * D + 2 * ui + 1] += f.y;
    } else if (b < 2 * BATCH) {
        int bb = b - BATCH;
        float2 f = __half22float2(emb[((size_t)(N_USERS + items[bb])) * 32 + ui]);
        i_acc[(size_t)bb * D + 2 * ui]     += f.x;
        i_acc[(size_t)bb * D + 2 * ui + 1] += f.y;
    }
}

__global__ void final_dot_kernel(const float* __restrict__ u_acc,
                                 const float* __restrict__ i_acc,
                                 float* __restrict__ out) {
    int gid = blockIdx.x * blockDim.x + threadIdx.x;
    int b = gid >> 6;
    int lane = gid & 63;
    if (b >= BATCH) return;
    float p = u_acc[(size_t)b * D + lane] * i_acc[(size_t)b * D + lane];
#pragma unroll
    for (int o = 32; o; o >>= 1) p += __shfl_xor(p, o, 64);
    if (lane == 0) out[b] = p * (1.0f / 16.0f);
}

// ---------------- launch ----------------

extern "C" void kernel_launch(void* const* d_in, const int* in_sizes, int n_in,
                              void* d_out, int out_size, void* d_ws, size_t ws_size,
                              hipStream_t stream) {
    const int*   users = (const int*)d_in[0];
    const int*   items = (const int*)d_in[1];
    const float* ue    = (const float*)d_in[2];
    const float* ie    = (const float*)d_in[3];
    const int*   rows  = (const int*)d_in[4];
    const int*   cols  = (const int*)d_in[5];
    const float* vals  = (const float*)d_in[6];
    float*       out   = (float*)d_out;

    char* ws = (char*)d_ws;
    size_t off = 0;
    auto alloc = [&](size_t bytes) {
        void* p = ws + off;
        off += (bytes + 255) & ~(size_t)255;
        return p;
    };
    const size_t NBH = (size_t)N_TOTAL * D * sizeof(unsigned short);  // 19.2 MB f16
    const size_t NEDGE = (size_t)NNZ + (size_t)NBUCKETS * PADB;       // padded edges
    char*  embA      = (char*)alloc(NBH);
    char*  embB      = (char*)alloc(NBH);
    float* u_acc     = (float*)alloc((size_t)BATCH * D * sizeof(float));
    float* i_acc     = (float*)alloc((size_t)BATCH * D * sizeof(float));
    int*   row_start = (int*)alloc(((size_t)N_TOTAL + 1) * sizeof(int));
    int*   bucketcnt = (int*)alloc((size_t)NBUCKETS * sizeof(int));
    int*   bucketoff = (int*)alloc(((size_t)NBUCKETS + 1) * sizeof(int));
    int*   cursor    = (int*)alloc((size_t)NBUCKETS * sizeof(int));
    int2*  edges     = (int2*)alloc(NEDGE * sizeof(int2));
    int2*  bucketed  = (int2*)alloc((size_t)NNZ * sizeof(int2));

    // init
    {
        size_t tot4 = (size_t)N_TOTAL * D / 4;
        init_emb_kernel<<<(unsigned)((tot4 + 255) / 256), 256, 0, stream>>>(
            (const float4*)ue, (const float4*)ie, (uint2*)embA);
        init_acc_kernel<<<(2 * BATCH * D + 255) / 256, 256, 0, stream>>>(
            users, items, ue, ie, u_acc, i_acc);
    }

    // CSR build (two-level bucketing, LDS-staged coalesced scatter)
    hipMemsetAsync(bucketcnt, 0, (size_t)NBUCKETS * sizeof(int), stream);
    bucket_hist_kernel<<<512, 256, 0, stream>>>(rows, bucketcnt);
    bucket_scan_kernel<<<1, 1024, 0, stream>>>(bucketcnt, bucketoff, cursor);
    bucket_scatter_kernel<<<SCAT_BLOCKS, SCAT_THREADS, 0, stream>>>(
        rows, cols, vals, cursor, bucketed);
    local_sort_kernel<<<NBUCKETS, LS_THREADS, 0, stream>>>(
        bucketoff, bucketed, row_start, edges);

    // Layer 1: embA -> embB
    spmm_csr_kernel<<<(N_TOTAL * 64 + 255) / 256, 256, 0, stream>>>(
        row_start, edges, embA, (uint2*)embB);
    gather_acc_kernel<<<(2 * BATCH * 32 + 255) / 256, 256, 0, stream>>>(
        users, items, (const __half2*)embB, u_acc, i_acc);

    // Layer 2: embB -> embA
    spmm_csr_kernel<<<(N_TOTAL * 64 + 255) / 256, 256, 0, stream>>>(
        row_start, edges, embB, (uint2*)embA);
    gather_acc_kernel<<<(2 * BATCH * 32 + 255) / 256, 256, 0, stream>>>(
        users, items, (const __half2*)embA, u_acc, i_acc);

    // Layer 3: only the 8192 batch rows, straight into accs
    layer3_kernel<<<(2 * BATCH * 64 + 255) / 256, 256, 0, stream>>>(
        users, items, row_start, edges, embA, u_acc, i_acc);

    final_dot_kernel<<<(BATCH * 64 + 255) / 256, 256, 0, stream>>>(u_acc, i_acc, out);
}

// Round 12
// 416.642 us; speedup vs baseline: 1.8713x; 1.4592x over previous
//
#include <hip/hip_runtime.h>

#define N_USERS 100000
#define M_ITEMS 50000
#define N_TOTAL (N_USERS + M_ITEMS)
#define D 64
#define NNZ 4000000
#define BATCH 4096

#define RPB 128                                   // rows per bucket (pow2)
#define BSHIFT 7
#define NBUCKETS ((N_TOTAL + RPB - 1) / RPB)      // 1172
#define BCAP 7680                                 // LDS edge capacity per bucket

#define TILE 8192                                 // edges per scatter block
#define SCAT_BLOCKS ((NNZ + TILE - 1) / TILE)     // 489
#define SCAT_THREADS 512
#define EPT (TILE / SCAT_THREADS)                 // 16 edges per thread
#define CPB 3                                     // buckets per thread in block scan

#define LS_THREADS 512
#define LS_EPT 16

// ---- bf16 helpers (RNE) ----
__device__ __forceinline__ unsigned pack_bf16(float a, float b) {
    unsigned ua = __float_as_uint(a);
    unsigned ub = __float_as_uint(b);
    ua = (ua + 0x7FFFu + ((ua >> 16) & 1u)) >> 16;
    ub = (ub + 0x7FFFu + ((ub >> 16) & 1u)) & 0xFFFF0000u;
    return ua | ub;
}
__device__ __forceinline__ float bf16_lo(unsigned p) { return __uint_as_float(p << 16); }
__device__ __forceinline__ float bf16_hi(unsigned p) { return __uint_as_float(p & 0xFFFF0000u); }

// ---------------- init ----------------

// Concatenate + convert fp32 embeddings to packed bf16 (2 dims per uint).
__global__ void init_emb_kernel(const float4* __restrict__ ue,
                                const float4* __restrict__ ie,
                                uint2* __restrict__ emb) {
    size_t i = (size_t)blockIdx.x * blockDim.x + threadIdx.x;  // one float4 -> uint2
    const size_t nu4  = (size_t)N_USERS * D / 4;
    const size_t tot4 = (size_t)N_TOTAL * D / 4;
    if (i >= tot4) return;
    float4 f = (i < nu4) ? ue[i] : ie[i - nu4];
    emb[i] = make_uint2(pack_bf16(f.x, f.y), pack_bf16(f.z, f.w));
}

__global__ void init_acc_kernel(const int* __restrict__ users,
                                const int* __restrict__ items,
                                const float* __restrict__ ue,
                                const float* __restrict__ ie,
                                float* __restrict__ u_acc,
                                float* __restrict__ i_acc) {
    int gid = blockIdx.x * blockDim.x + threadIdx.x;  // 2*BATCH*D threads
    int d = gid & (D - 1);
    int b = gid >> 6;
    if (b < BATCH) {
        u_acc[(size_t)b * D + d] = ue[(size_t)users[b] * D + d];
    } else if (b < 2 * BATCH) {
        int bb = b - BATCH;
        i_acc[(size_t)bb * D + d] = ie[(size_t)items[bb] * D + d];
    }
}

// ---------------- CSR build: two-level bucketing ----------------

__global__ void bucket_hist_kernel(const int* __restrict__ rows,
                                   int* __restrict__ bucketcnt) {
    __shared__ int h[NBUCKETS];
    for (int i = threadIdx.x; i < NBUCKETS; i += blockDim.x) h[i] = 0;
    __syncthreads();
    int stride = gridDim.x * blockDim.x;
    for (int e = blockIdx.x * blockDim.x + threadIdx.x; e < NNZ; e += stride)
        atomicAdd(&h[rows[e] >> BSHIFT], 1);
    __syncthreads();
    for (int i = threadIdx.x; i < NBUCKETS; i += blockDim.x)
        if (h[i]) atomicAdd(&bucketcnt[i], h[i]);
}

__global__ void bucket_scan_kernel(const int* __restrict__ cnt,
                                   int* __restrict__ bucketoff,
                                   int* __restrict__ cursor) {
    __shared__ int sc[1024];
    int t = threadIdx.x;
    int i0 = t * 2, i1 = t * 2 + 1;
    int a = (i0 < NBUCKETS) ? cnt[i0] : 0;
    int b = (i1 < NBUCKETS) ? cnt[i1] : 0;
    sc[t] = a + b;
    __syncthreads();
    for (int o = 1; o < 1024; o <<= 1) {
        int v = (t >= o) ? sc[t - o] : 0;
        __syncthreads();
        sc[t] += v;
        __syncthreads();
    }
    int excl = (t == 0) ? 0 : sc[t - 1];
    if (i0 < NBUCKETS) { bucketoff[i0] = excl;     cursor[i0] = excl; }
    if (i1 < NBUCKETS) { bucketoff[i1] = excl + a; cursor[i1] = excl + a; }
    if (t == 0) bucketoff[NBUCKETS] = NNZ;
}

// Tile-aggregated scatter with LDS staging; lane-parallel coalesced stream-out.
__global__ __launch_bounds__(SCAT_THREADS)
void bucket_scatter_kernel(const int* __restrict__ rows,
                           const int* __restrict__ cols,
                           const float* __restrict__ vals,
                           int* __restrict__ cursor,
                           int2* __restrict__ bucketed) {
    __shared__ int hist[NBUCKETS];        // counts, then global base per bucket
    __shared__ int loff[NBUCKETS + 1];    // local exclusive prefix
    __shared__ int partial[SCAT_THREADS];
    __shared__ int2 buf[TILE];            // 64 KB
    __shared__ int dst[TILE];             // 32 KB
    int t = threadIdx.x;
    size_t start = (size_t)blockIdx.x * TILE;
    int n = (int)(((size_t)NNZ - start < TILE) ? ((size_t)NNZ - start) : TILE);

    for (int i = t; i < NBUCKETS; i += SCAT_THREADS) hist[i] = 0;
    __syncthreads();
    // Phase A: histogram; atomicAdd's return IS the local rank.
    int rowv[EPT];
    int rank[EPT];
#pragma unroll
    for (int k = 0; k < EPT; ++k) {
        int i = t + k * SCAT_THREADS;
        if (i < n) {
            int r = rows[start + i];
            rowv[k] = r;
            rank[k] = atomicAdd(&hist[r >> BSHIFT], 1);
        }
    }
    __syncthreads();
    // Phase B1: block scan hist -> loff (exclusive)
    {
        int base = t * CPB;
        int s = 0;
#pragma unroll
        for (int j = 0; j < CPB; ++j) {
            int idx = base + j;
            if (idx < NBUCKETS) s += hist[idx];
        }
        partial[t] = s;
        __syncthreads();
        for (int o = 1; o < SCAT_THREADS; o <<= 1) {
            int v = (t >= o) ? partial[t - o] : 0;
            __syncthreads();
            partial[t] += v;
            __syncthreads();
        }
        int excl = (t == 0) ? 0 : partial[t - 1];
#pragma unroll
        for (int j = 0; j < CPB; ++j) {
            int idx = base + j;
            if (idx < NBUCKETS) { loff[idx] = excl; excl += hist[idx]; }
        }
        if (t == 0) loff[NBUCKETS] = n;
    }
    __syncthreads();
    // Phase B2: one global reservation per touched bucket; hist becomes gbase.
    for (int i = t; i < NBUCKETS; i += SCAT_THREADS) {
        int c = loff[i + 1] - loff[i];
        hist[i] = c ? atomicAdd(&cursor[i], c) : 0;
    }
    __syncthreads();
    // Phase C: place edges bucket-sorted in LDS; record global dest per slot.
#pragma unroll
    for (int k = 0; k < EPT; ++k) {
        int i = t + k * SCAT_THREADS;
        if (i < n) {
            int r = rowv[k];
            int bkt = r >> BSHIFT;
            int slot = loff[bkt] + rank[k];
            buf[slot] = make_int2(((r & (RPB - 1)) << 18) | cols[start + i],
                                  __float_as_int(vals[start + i]));
            dst[slot] = hist[bkt] + rank[k];
        }
    }
    __syncthreads();
    // Phase D: lane-parallel coalesced stream-out.
    for (int i = t; i < n; i += SCAT_THREADS)
        bucketed[dst[i]] = buf[i];
}

// Per-bucket counting sort in LDS (rank fused, payload held in registers).
// Output edge format (R9-proven): x = col byte offset (col*128), y = f32 val.
__global__ __launch_bounds__(LS_THREADS)
void local_sort_kernel(const int* __restrict__ bucketoff,
                       const int2* __restrict__ bucketed,
                       int* __restrict__ row_start,
                       int2* __restrict__ edges) {
    __shared__ int hist[RPB];
    __shared__ int sc[RPB];
    __shared__ int2 buf[BCAP];
    int b = blockIdx.x;
    int t = threadIdx.x;
    int s = bucketoff[b], e = bucketoff[b + 1], n = e - s;

    if (t < RPB) hist[t] = 0;
    __syncthreads();
    int rl[LS_EPT], rank[LS_EPT];
    int2 pay[LS_EPT];
#pragma unroll
    for (int k = 0; k < LS_EPT; ++k) {
        int i = t + k * LS_THREADS;
        if (i < n) {
            int2 ev = bucketed[s + i];
            rl[k] = (int)((unsigned)ev.x >> 18);
            pay[k] = make_int2((ev.x & 0x3FFFF) << 7, ev.y);
            rank[k] = atomicAdd(&hist[rl[k]], 1);
        }
    }
    __syncthreads();
    if (t < RPB) sc[t] = hist[t];
    __syncthreads();
    for (int o = 1; o < RPB; o <<= 1) {
        int v = (t < RPB && t >= o) ? sc[t - o] : 0;
        __syncthreads();
        if (t < RPB) sc[t] += v;
        __syncthreads();
    }
    if (t < RPB) {
        int excl = (t == 0) ? 0 : sc[t - 1];
        int gr = b * RPB + t;
        if (gr < N_TOTAL) row_start[gr] = s + excl;
    }
    if (b == 0 && t == 0) row_start[N_TOTAL] = NNZ;
    __syncthreads();
#pragma unroll
    for (int k = 0; k < LS_EPT; ++k) {
        int i = t + k * LS_THREADS;
        if (i < n) {
            int excl = (rl[k] == 0) ? 0 : sc[rl[k] - 1];
            int p = excl + rank[k];
            if (p < BCAP) buf[p] = pay[k];
            else          edges[s + p] = pay[k];
        }
    }
    __syncthreads();
    int m = (n < BCAP) ? n : BCAP;
    for (int i = t; i < m; i += LS_THREADS) edges[s + i] = buf[i];
}

// ---------------- bf16 CSR SpMM, quarter-split (R9-proven) ----------------
// One wave per row. quad = lane>>4 processes edges 4t+quad; ui = lane&15
// covers dims 4ui..4ui+3 via one uint2 load (16 lanes x 8 B = 128 B/edge).
__global__ void spmm_csr_kernel(const int* __restrict__ row_start,
                                const int2* __restrict__ edges,   // x = col*128
                                const char* __restrict__ emb_in,  // bf16 rows, 128 B
                                uint2* __restrict__ emb_out) {
    int wave = (blockIdx.x * blockDim.x + threadIdx.x) >> 6;
    int lane = threadIdx.x & 63;
    if (wave >= N_TOTAL) return;
    int quad = lane >> 4;
    int ui   = lane & 15;
    int uioff = ui << 3;
    int s = row_start[wave];
    int e = row_start[wave + 1];
    float a0 = 0.f, a1 = 0.f, a2 = 0.f, a3 = 0.f;
    for (int base = s; base < e; base += 64) {
        int n = e - base; if (n > 64) n = 64;
        int c = 0; float v = 0.0f;
        if (base + lane < e) {
            int2 ev = edges[base + lane];
            c = ev.x; v = __int_as_float(ev.y);
        }
        int tmax = (n + 3) >> 2;
        for (int t = 0; t < tmax; ++t) {
            int j = 4 * t + quad;                  // < 64 always
            int   cj = __shfl(c, j, 64);
            float vj = __shfl(v, j, 64);
            float m  = (j < n) ? vj : 0.0f;
            uint2 p = *(const uint2*)(emb_in + cj + uioff);
            a0 += m * bf16_lo(p.x);
            a1 += m * bf16_hi(p.x);
            a2 += m * bf16_lo(p.y);
            a3 += m * bf16_hi(p.y);
        }
    }
    a0 += __shfl_xor(a0, 16, 64); a1 += __shfl_xor(a1, 16, 64);
    a2 += __shfl_xor(a2, 16, 64); a3 += __shfl_xor(a3, 16, 64);
    a0 += __shfl_xor(a0, 32, 64); a1 += __shfl_xor(a1, 32, 64);
    a2 += __shfl_xor(a2, 32, 64); a3 += __shfl_xor(a3, 32, 64);
    if (quad == 0)
        emb_out[(size_t)wave * 16 + ui] = make_uint2(pack_bf16(a0, a1),
                                                     pack_bf16(a2, a3));
}

// Layer-3: segment sums ONLY for the 8192 batch rows, added into fp32 accs.
__global__ void layer3_kernel(const int* __restrict__ users,
                              const int* __restrict__ items,
                              const int* __restrict__ row_start,
                              const int2* __restrict__ edges,
                              const char* __restrict__ emb_in,  // bf16 rows
                              float* __restrict__ u_acc,
                              float* __restrict__ i_acc) {
    int wave = (blockIdx.x * blockDim.x + threadIdx.x) >> 6;
    int lane = threadIdx.x & 63;
    if (wave >= 2 * BATCH) return;
    int quad = lane >> 4;
    int ui   = lane & 15;
    int uioff = ui << 3;
    int row;
    float* dstp;
    if (wave < BATCH) {
        row = users[wave];
        dstp = &u_acc[(size_t)wave * D];
    } else {
        int bb = wave - BATCH;
        row = N_USERS + items[bb];
        dstp = &i_acc[(size_t)bb * D];
    }
    int s = row_start[row];
    int e = row_start[row + 1];
    float a0 = 0.f, a1 = 0.f, a2 = 0.f, a3 = 0.f;
    for (int base = s; base < e; base += 64) {
        int n = e - base; if (n > 64) n = 64;
        int c = 0; float v = 0.0f;
        if (base + lane < e) {
            int2 ev = edges[base + lane];
            c = ev.x; v = __int_as_float(ev.y);
        }
        int tmax = (n + 3) >> 2;
        for (int t = 0; t < tmax; ++t) {
            int j = 4 * t + quad;
            int   cj = __shfl(c, j, 64);
            float vj = __shfl(v, j, 64);
            float m  = (j < n) ? vj : 0.0f;
            uint2 p = *(const uint2*)(emb_in + cj + uioff);
            a0 += m * bf16_lo(p.x);
            a1 += m * bf16_hi(p.x);
            a2 += m * bf16_lo(p.y);
            a3 += m * bf16_hi(p.y);
        }
    }
    a0 += __shfl_xor(a0, 16, 64); a1 += __shfl_xor(a1, 16, 64);
    a2 += __shfl_xor(a2, 16, 64); a3 += __shfl_xor(a3, 16, 64);
    a0 += __shfl_xor(a0, 32, 64); a1 += __shfl_xor(a1, 32, 64);
    a2 += __shfl_xor(a2, 32, 64); a3 += __shfl_xor(a3, 32, 64);
    if (quad == 0) {
        dstp[4 * ui + 0] += a0;
        dstp[4 * ui + 1] += a1;
        dstp[4 * ui + 2] += a2;
        dstp[4 * ui + 3] += a3;
    }
}

// After layers 1,2: pull bf16 emb rows at batch indices into fp32 accs.
__global__ void gather_acc_kernel(const int* __restrict__ users,
                                  const int* __restrict__ items,
                                  const unsigned* __restrict__ emb,  // bf16x2
                                  float* __restrict__ u_acc,
                                  float* __restrict__ i_acc) {
    int gid = blockIdx.x * blockDim.x + threadIdx.x;  // 2*BATCH*32 threads
    int ui = gid & 31;
    int b  = gid >> 5;
    if (b < BATCH) {
        unsigned p = emb[(size_t)users[b] * 32 + ui];
        u_acc[(size_t)b * D + 2 * ui]     += bf16_lo(p);
        u_acc[(size_t)b * D + 2 * ui + 1] += bf16_hi(p);
    } else if (b < 2 * BATCH) {
        int bb = b - BATCH;
        unsigned p = emb[((size_t)(N_USERS + items[bb])) * 32 + ui];
        i_acc[(size_t)bb * D + 2 * ui]     += bf16_lo(p);
        i_acc[(size_t)bb * D + 2 * ui + 1] += bf16_hi(p);
    }
}

__global__ void final_dot_kernel(const float* __restrict__ u_acc,
                                 const float* __restrict__ i_acc,
                                 float* __restrict__ out) {
    int gid = blockIdx.x * blockDim.x + threadIdx.x;
    int b = gid >> 6;
    int lane = gid & 63;
    if (b >= BATCH) return;
    float p = u_acc[(size_t)b * D + lane] * i_acc[(size_t)b * D + lane];
#pragma unroll
    for (int o = 32; o; o >>= 1) p += __shfl_xor(p, o, 64);
    if (lane == 0) out[b] = p * (1.0f / 16.0f);
}

// ---------------- launch ----------------

extern "C" void kernel_launch(void* const* d_in, const int* in_sizes, int n_in,
                              void* d_out, int out_size, void* d_ws, size_t ws_size,
                              hipStream_t stream) {
    const int*   users = (const int*)d_in[0];
    const int*   items = (const int*)d_in[1];
    const float* ue    = (const float*)d_in[2];
    const float* ie    = (const float*)d_in[3];
    const int*   rows  = (const int*)d_in[4];
    const int*   cols  = (const int*)d_in[5];
    const float* vals  = (const float*)d_in[6];
    float*       out   = (float*)d_out;

    char* ws = (char*)d_ws;
    size_t off = 0;
    auto alloc = [&](size_t bytes) {
        void* p = ws + off;
        off += (bytes + 255) & ~(size_t)255;
        return p;
    };
    const size_t NBH = (size_t)N_TOTAL * D * sizeof(unsigned short);  // 19.2 MB bf16
    char*  embA      = (char*)alloc(NBH);
    char*  embB      = (char*)alloc(NBH);
    float* u_acc     = (float*)alloc((size_t)BATCH * D * sizeof(float));
    float* i_acc     = (float*)alloc((size_t)BATCH * D * sizeof(float));
    int*   row_start = (int*)alloc(((size_t)N_TOTAL + 1) * sizeof(int));
    int*   bucketcnt = (int*)alloc((size_t)NBUCKETS * sizeof(int));
    int*   bucketoff = (int*)alloc(((size_t)NBUCKETS + 1) * sizeof(int));
    int*   cursor    = (int*)alloc((size_t)NBUCKETS * sizeof(int));
    int2*  edges     = (int2*)alloc((size_t)NNZ * sizeof(int2));
    int2*  bucketed  = (int2*)alloc((size_t)NNZ * sizeof(int2));

    // init
    {
        size_t tot4 = (size_t)N_TOTAL * D / 4;
        init_emb_kernel<<<(unsigned)((tot4 + 255) / 256), 256, 0, stream>>>(
            (const float4*)ue, (const float4*)ie, (uint2*)embA);
        init_acc_kernel<<<(2 * BATCH * D + 255) / 256, 256, 0, stream>>>(
            users, items, ue, ie, u_acc, i_acc);
    }

    // CSR build (two-level bucketing, LDS-staged coalesced scatter)
    hipMemsetAsync(bucketcnt, 0, (size_t)NBUCKETS * sizeof(int), stream);
    bucket_hist_kernel<<<512, 256, 0, stream>>>(rows, bucketcnt);
    bucket_scan_kernel<<<1, 1024, 0, stream>>>(bucketcnt, bucketoff, cursor);
    bucket_scatter_kernel<<<SCAT_BLOCKS, SCAT_THREADS, 0, stream>>>(
        rows, cols, vals, cursor, bucketed);
    local_sort_kernel<<<NBUCKETS, LS_THREADS, 0, stream>>>(
        bucketoff, bucketed, row_start, edges);

    // Layer 1: embA -> embB
    spmm_csr_kernel<<<(N_TOTAL * 64 + 255) / 256, 256, 0, stream>>>(
        row_start, edges, embA, (uint2*)embB);
    gather_acc_kernel<<<(2 * BATCH * 32 + 255) / 256, 256, 0, stream>>>(
        users, items, (const unsigned*)embB, u_acc, i_acc);

    // Layer 2: embB -> embA
    spmm_csr_kernel<<<(N_TOTAL * 64 + 255) / 256, 256, 0, stream>>>(
        row_start, edges, embB, (uint2*)embA);
    gather_acc_kernel<<<(2 * BATCH * 32 + 255) / 256, 256, 0, stream>>>(
        users, items, (const unsigned*)embA, u_acc, i_acc);

    // Layer 3: only the 8192 batch rows, straight into accs
    layer3_kernel<<<(2 * BATCH * 64 + 255) / 256, 256, 0, stream>>>(
        users, items, row_start, edges, embA, u_acc, i_acc);

    final_dot_kernel<<<(BATCH * 64 + 255) / 256, 256, 0, stream>>>(u_acc, i_acc, out);
}

// Round 13
// 374.140 us; speedup vs baseline: 2.0839x; 1.1136x over previous
//
#include <hip/hip_runtime.h>

#define N_USERS 100000
#define M_ITEMS 50000
#define N_TOTAL (N_USERS + M_ITEMS)
#define D 64
#define NNZ 4000000
#define BATCH 4096

#define RPB 128                                   // rows per bucket (pow2)
#define BSHIFT 7
#define NBUCKETS ((N_TOTAL + RPB - 1) / RPB)      // 1172
#define BCAP 7680                                 // LDS edge capacity per bucket

#define TILE 8192                                 // edges per scatter block
#define SCAT_BLOCKS ((NNZ + TILE - 1) / TILE)     // 489
#define SCAT_THREADS 512
#define EPT (TILE / SCAT_THREADS)                 // 16 edges per thread
#define CPB 3                                     // buckets per thread in block scan

#define LS_THREADS 512
#define LS_EPT 16

// ---- bf16 helpers (RNE) ----
__device__ __forceinline__ unsigned pack_bf16(float a, float b) {
    unsigned ua = __float_as_uint(a);
    unsigned ub = __float_as_uint(b);
    ua = (ua + 0x7FFFu + ((ua >> 16) & 1u)) >> 16;
    ub = (ub + 0x7FFFu + ((ub >> 16) & 1u)) & 0xFFFF0000u;
    return ua | ub;
}
__device__ __forceinline__ float bf16_lo(unsigned p) { return __uint_as_float(p << 16); }
__device__ __forceinline__ float bf16_hi(unsigned p) { return __uint_as_float(p & 0xFFFF0000u); }

// ---------------- init ----------------

// Concatenate + convert fp32 embeddings to packed bf16 (2 dims per uint).
__global__ void init_emb_kernel(const float4* __restrict__ ue,
                                const float4* __restrict__ ie,
                                uint2* __restrict__ emb) {
    size_t i = (size_t)blockIdx.x * blockDim.x + threadIdx.x;  // one float4 -> uint2
    const size_t nu4  = (size_t)N_USERS * D / 4;
    const size_t tot4 = (size_t)N_TOTAL * D / 4;
    if (i >= tot4) return;
    float4 f = (i < nu4) ? ue[i] : ie[i - nu4];
    emb[i] = make_uint2(pack_bf16(f.x, f.y), pack_bf16(f.z, f.w));
}

__global__ void init_acc_kernel(const int* __restrict__ users,
                                const int* __restrict__ items,
                                const float* __restrict__ ue,
                                const float* __restrict__ ie,
                                float* __restrict__ u_acc,
                                float* __restrict__ i_acc) {
    int gid = blockIdx.x * blockDim.x + threadIdx.x;  // 2*BATCH*D threads
    int d = gid & (D - 1);
    int b = gid >> 6;
    if (b < BATCH) {
        u_acc[(size_t)b * D + d] = ue[(size_t)users[b] * D + d];
    } else if (b < 2 * BATCH) {
        int bb = b - BATCH;
        i_acc[(size_t)bb * D + d] = ie[(size_t)items[bb] * D + d];
    }
}

// ---------------- CSR build: two-level bucketing ----------------

__global__ void bucket_hist_kernel(const int* __restrict__ rows,
                                   int* __restrict__ bucketcnt) {
    __shared__ int h[NBUCKETS];
    for (int i = threadIdx.x; i < NBUCKETS; i += blockDim.x) h[i] = 0;
    __syncthreads();
    int stride = gridDim.x * blockDim.x;
    for (int e = blockIdx.x * blockDim.x + threadIdx.x; e < NNZ; e += stride)
        atomicAdd(&h[rows[e] >> BSHIFT], 1);
    __syncthreads();
    for (int i = threadIdx.x; i < NBUCKETS; i += blockDim.x)
        if (h[i]) atomicAdd(&bucketcnt[i], h[i]);
}

__global__ void bucket_scan_kernel(const int* __restrict__ cnt,
                                   int* __restrict__ bucketoff,
                                   int* __restrict__ cursor) {
    __shared__ int sc[1024];
    int t = threadIdx.x;
    int i0 = t * 2, i1 = t * 2 + 1;
    int a = (i0 < NBUCKETS) ? cnt[i0] : 0;
    int b = (i1 < NBUCKETS) ? cnt[i1] : 0;
    sc[t] = a + b;
    __syncthreads();
    for (int o = 1; o < 1024; o <<= 1) {
        int v = (t >= o) ? sc[t - o] : 0;
        __syncthreads();
        sc[t] += v;
        __syncthreads();
    }
    int excl = (t == 0) ? 0 : sc[t - 1];
    if (i0 < NBUCKETS) { bucketoff[i0] = excl;     cursor[i0] = excl; }
    if (i1 < NBUCKETS) { bucketoff[i1] = excl + a; cursor[i1] = excl + a; }
    if (t == 0) bucketoff[NBUCKETS] = NNZ;
}

// Tile-aggregated scatter with LDS staging; lane-parallel coalesced stream-out.
__global__ __launch_bounds__(SCAT_THREADS)
void bucket_scatter_kernel(const int* __restrict__ rows,
                           const int* __restrict__ cols,
                           const float* __restrict__ vals,
                           int* __restrict__ cursor,
                           int2* __restrict__ bucketed) {
    __shared__ int hist[NBUCKETS];        // counts, then global base per bucket
    __shared__ int loff[NBUCKETS + 1];    // local exclusive prefix
    __shared__ int partial[SCAT_THREADS];
    __shared__ int2 buf[TILE];            // 64 KB
    __shared__ int dst[TILE];             // 32 KB
    int t = threadIdx.x;
    size_t start = (size_t)blockIdx.x * TILE;
    int n = (int)(((size_t)NNZ - start < TILE) ? ((size_t)NNZ - start) : TILE);

    for (int i = t; i < NBUCKETS; i += SCAT_THREADS) hist[i] = 0;
    __syncthreads();
    // Phase A: histogram; atomicAdd's return IS the local rank.
    int rowv[EPT];
    int rank[EPT];
#pragma unroll
    for (int k = 0; k < EPT; ++k) {
        int i = t + k * SCAT_THREADS;
        if (i < n) {
            int r = rows[start + i];
            rowv[k] = r;
            rank[k] = atomicAdd(&hist[r >> BSHIFT], 1);
        }
    }
    __syncthreads();
    // Phase B1: block scan hist -> loff (exclusive)
    {
        int base = t * CPB;
        int s = 0;
#pragma unroll
        for (int j = 0; j < CPB; ++j) {
            int idx = base + j;
            if (idx < NBUCKETS) s += hist[idx];
        }
        partial[t] = s;
        __syncthreads();
        for (int o = 1; o < SCAT_THREADS; o <<= 1) {
            int v = (t >= o) ? partial[t - o] : 0;
            __syncthreads();
            partial[t] += v;
            __syncthreads();
        }
        int excl = (t == 0) ? 0 : partial[t - 1];
#pragma unroll
        for (int j = 0; j < CPB; ++j) {
            int idx = base + j;
            if (idx < NBUCKETS) { loff[idx] = excl; excl += hist[idx]; }
        }
        if (t == 0) loff[NBUCKETS] = n;
    }
    __syncthreads();
    // Phase B2: one global reservation per touched bucket; hist becomes gbase.
    for (int i = t; i < NBUCKETS; i += SCAT_THREADS) {
        int c = loff[i + 1] - loff[i];
        hist[i] = c ? atomicAdd(&cursor[i], c) : 0;
    }
    __syncthreads();
    // Phase C: place edges bucket-sorted in LDS; record global dest per slot.
#pragma unroll
    for (int k = 0; k < EPT; ++k) {
        int i = t + k * SCAT_THREADS;
        if (i < n) {
            int r = rowv[k];
            int bkt = r >> BSHIFT;
            int slot = loff[bkt] + rank[k];
            buf[slot] = make_int2(((r & (RPB - 1)) << 18) | cols[start + i],
                                  __float_as_int(vals[start + i]));
            dst[slot] = hist[bkt] + rank[k];
        }
    }
    __syncthreads();
    // Phase D: lane-parallel coalesced stream-out.
    for (int i = t; i < n; i += SCAT_THREADS)
        bucketed[dst[i]] = buf[i];
}

// Per-bucket counting sort in LDS (rank fused, payload held in registers).
// Output edge format: x = col byte offset (col*128), y = f32 val.
__global__ __launch_bounds__(LS_THREADS)
void local_sort_kernel(const int* __restrict__ bucketoff,
                       const int2* __restrict__ bucketed,
                       int* __restrict__ row_start,
                       int2* __restrict__ edges) {
    __shared__ int hist[RPB];
    __shared__ int sc[RPB];
    __shared__ int2 buf[BCAP];
    int b = blockIdx.x;
    int t = threadIdx.x;
    int s = bucketoff[b], e = bucketoff[b + 1], n = e - s;

    if (t < RPB) hist[t] = 0;
    __syncthreads();
    int rl[LS_EPT], rank[LS_EPT];
    int2 pay[LS_EPT];
#pragma unroll
    for (int k = 0; k < LS_EPT; ++k) {
        int i = t + k * LS_THREADS;
        if (i < n) {
            int2 ev = bucketed[s + i];
            rl[k] = (int)((unsigned)ev.x >> 18);
            pay[k] = make_int2((ev.x & 0x3FFFF) << 7, ev.y);
            rank[k] = atomicAdd(&hist[rl[k]], 1);
        }
    }
    __syncthreads();
    if (t < RPB) sc[t] = hist[t];
    __syncthreads();
    for (int o = 1; o < RPB; o <<= 1) {
        int v = (t < RPB && t >= o) ? sc[t - o] : 0;
        __syncthreads();
        if (t < RPB) sc[t] += v;
        __syncthreads();
    }
    if (t < RPB) {
        int excl = (t == 0) ? 0 : sc[t - 1];
        int gr = b * RPB + t;
        if (gr < N_TOTAL) row_start[gr] = s + excl;
    }
    if (b == 0 && t == 0) row_start[N_TOTAL] = NNZ;
    __syncthreads();
#pragma unroll
    for (int k = 0; k < LS_EPT; ++k) {
        int i = t + k * LS_THREADS;
        if (i < n) {
            int excl = (rl[k] == 0) ? 0 : sc[rl[k] - 1];
            int p = excl + rank[k];
            if (p < BCAP) buf[p] = pay[k];
            else          edges[s + p] = pay[k];
        }
    }
    __syncthreads();
    int m = (n < BCAP) ? n : BCAP;
    for (int i = t; i < m; i += LS_THREADS) edges[s + i] = buf[i];
}

// ---------------- bf16 CSR SpMM, quarter-split, unroll-4 MLP ----------------
// One wave per row. quad = lane>>4 processes edges 4t+quad; ui = lane&15
// covers dims 4ui..4ui+3 via one uint2 load. Inner loop manually unrolled
// x4 with all gathers issued before consumption (4 loads in flight/lane).
__global__ void spmm_csr_kernel(const int* __restrict__ row_start,
                                const int2* __restrict__ edges,   // x = col*128
                                const char* __restrict__ emb_in,  // bf16 rows, 128 B
                                uint2* __restrict__ emb_out) {
    int wave = (blockIdx.x * blockDim.x + threadIdx.x) >> 6;
    int lane = threadIdx.x & 63;
    if (wave >= N_TOTAL) return;
    int quad = lane >> 4;
    int ui   = lane & 15;
    int uioff = ui << 3;
    int s = row_start[wave];
    int e = row_start[wave + 1];
    float a0 = 0.f, a1 = 0.f, a2 = 0.f, a3 = 0.f;
    for (int base = s; base < e; base += 64) {
        int n = e - base; if (n > 64) n = 64;
        int c = 0; float v = 0.0f;
        if (base + lane < e) {
            int2 ev = edges[base + lane];
            c = ev.x; v = __int_as_float(ev.y);
        }
        int tmax = (n + 3) >> 2;
        int t = 0;
        for (; t + 4 <= tmax; t += 4) {
            int j0 = 4 * t + quad, j1 = j0 + 4, j2 = j0 + 8, j3 = j0 + 12;
            int   c0 = __shfl(c, j0, 64), c1 = __shfl(c, j1, 64);
            int   c2 = __shfl(c, j2, 64), c3 = __shfl(c, j3, 64);
            float v0 = __shfl(v, j0, 64), v1 = __shfl(v, j1, 64);
            float v2 = __shfl(v, j2, 64), v3 = __shfl(v, j3, 64);
            uint2 p0 = *(const uint2*)(emb_in + c0 + uioff);
            uint2 p1 = *(const uint2*)(emb_in + c1 + uioff);
            uint2 p2 = *(const uint2*)(emb_in + c2 + uioff);
            uint2 p3 = *(const uint2*)(emb_in + c3 + uioff);
            float m0 = (j0 < n) ? v0 : 0.0f;
            float m1 = (j1 < n) ? v1 : 0.0f;
            float m2 = (j2 < n) ? v2 : 0.0f;
            float m3 = (j3 < n) ? v3 : 0.0f;
            a0 += m0 * bf16_lo(p0.x); a1 += m0 * bf16_hi(p0.x);
            a2 += m0 * bf16_lo(p0.y); a3 += m0 * bf16_hi(p0.y);
            a0 += m1 * bf16_lo(p1.x); a1 += m1 * bf16_hi(p1.x);
            a2 += m1 * bf16_lo(p1.y); a3 += m1 * bf16_hi(p1.y);
            a0 += m2 * bf16_lo(p2.x); a1 += m2 * bf16_hi(p2.x);
            a2 += m2 * bf16_lo(p2.y); a3 += m2 * bf16_hi(p2.y);
            a0 += m3 * bf16_lo(p3.x); a1 += m3 * bf16_hi(p3.x);
            a2 += m3 * bf16_lo(p3.y); a3 += m3 * bf16_hi(p3.y);
        }
        for (; t < tmax; ++t) {
            int j = 4 * t + quad;
            int   cj = __shfl(c, j, 64);
            float vj = __shfl(v, j, 64);
            float m  = (j < n) ? vj : 0.0f;
            uint2 p = *(const uint2*)(emb_in + cj + uioff);
            a0 += m * bf16_lo(p.x);
            a1 += m * bf16_hi(p.x);
            a2 += m * bf16_lo(p.y);
            a3 += m * bf16_hi(p.y);
        }
    }
    a0 += __shfl_xor(a0, 16, 64); a1 += __shfl_xor(a1, 16, 64);
    a2 += __shfl_xor(a2, 16, 64); a3 += __shfl_xor(a3, 16, 64);
    a0 += __shfl_xor(a0, 32, 64); a1 += __shfl_xor(a1, 32, 64);
    a2 += __shfl_xor(a2, 32, 64); a3 += __shfl_xor(a3, 32, 64);
    if (quad == 0)
        emb_out[(size_t)wave * 16 + ui] = make_uint2(pack_bf16(a0, a1),
                                                     pack_bf16(a2, a3));
}

// Layer-3: segment sums ONLY for the 8192 batch rows, added into fp32 accs.
__global__ void layer3_kernel(const int* __restrict__ users,
                              const int* __restrict__ items,
                              const int* __restrict__ row_start,
                              const int2* __restrict__ edges,
                              const char* __restrict__ emb_in,  // bf16 rows
                              float* __restrict__ u_acc,
                              float* __restrict__ i_acc) {
    int wave = (blockIdx.x * blockDim.x + threadIdx.x) >> 6;
    int lane = threadIdx.x & 63;
    if (wave >= 2 * BATCH) return;
    int quad = lane >> 4;
    int ui   = lane & 15;
    int uioff = ui << 3;
    int row;
    float* dstp;
    if (wave < BATCH) {
        row = users[wave];
        dstp = &u_acc[(size_t)wave * D];
    } else {
        int bb = wave - BATCH;
        row = N_USERS + items[bb];
        dstp = &i_acc[(size_t)bb * D];
    }
    int s = row_start[row];
    int e = row_start[row + 1];
    float a0 = 0.f, a1 = 0.f, a2 = 0.f, a3 = 0.f;
    for (int base = s; base < e; base += 64) {
        int n = e - base; if (n > 64) n = 64;
        int c = 0; float v = 0.0f;
        if (base + lane < e) {
            int2 ev = edges[base + lane];
            c = ev.x; v = __int_as_float(ev.y);
        }
        int tmax = (n + 3) >> 2;
        int t = 0;
        for (; t + 4 <= tmax; t += 4) {
            int j0 = 4 * t + quad, j1 = j0 + 4, j2 = j0 + 8, j3 = j0 + 12;
            int   c0 = __shfl(c, j0, 64), c1 = __shfl(c, j1, 64);
            int   c2 = __shfl(c, j2, 64), c3 = __shfl(c, j3, 64);
            float v0 = __shfl(v, j0, 64), v1 = __shfl(v, j1, 64);
            float v2 = __shfl(v, j2, 64), v3 = __shfl(v, j3, 64);
            uint2 p0 = *(const uint2*)(emb_in + c0 + uioff);
            uint2 p1 = *(const uint2*)(emb_in + c1 + uioff);
            uint2 p2 = *(const uint2*)(emb_in + c2 + uioff);
            uint2 p3 = *(const uint2*)(emb_in + c3 + uioff);
            float m0 = (j0 < n) ? v0 : 0.0f;
            float m1 = (j1 < n) ? v1 : 0.0f;
            float m2 = (j2 < n) ? v2 : 0.0f;
            float m3 = (j3 < n) ? v3 : 0.0f;
            a0 += m0 * bf16_lo(p0.x); a1 += m0 * bf16_hi(p0.x);
            a2 += m0 * bf16_lo(p0.y); a3 += m0 * bf16_hi(p0.y);
            a0 += m1 * bf16_lo(p1.x); a1 += m1 * bf16_hi(p1.x);
            a2 += m1 * bf16_lo(p1.y); a3 += m1 * bf16_hi(p1.y);
            a0 += m2 * bf16_lo(p2.x); a1 += m2 * bf16_hi(p2.x);
            a2 += m2 * bf16_lo(p2.y); a3 += m2 * bf16_hi(p2.y);
            a0 += m3 * bf16_lo(p3.x); a1 += m3 * bf16_hi(p3.x);
            a2 += m3 * bf16_lo(p3.y); a3 += m3 * bf16_hi(p3.y);
        }
        for (; t < tmax; ++t) {
            int j = 4 * t + quad;
            int   cj = __shfl(c, j, 64);
            float vj = __shfl(v, j, 64);
            float m  = (j < n) ? vj : 0.0f;
            uint2 p = *(const uint2*)(emb_in + cj + uioff);
            a0 += m * bf16_lo(p.x);
            a1 += m * bf16_hi(p.x);
            a2 += m * bf16_lo(p.y);
            a3 += m * bf16_hi(p.y);
        }
    }
    a0 += __shfl_xor(a0, 16, 64); a1 += __shfl_xor(a1, 16, 64);
    a2 += __shfl_xor(a2, 16, 64); a3 += __shfl_xor(a3, 16, 64);
    a0 += __shfl_xor(a0, 32, 64); a1 += __shfl_xor(a1, 32, 64);
    a2 += __shfl_xor(a2, 32, 64); a3 += __shfl_xor(a3, 32, 64);
    if (quad == 0) {
        dstp[4 * ui + 0] += a0;
        dstp[4 * ui + 1] += a1;
        dstp[4 * ui + 2] += a2;
        dstp[4 * ui + 3] += a3;
    }
}

// After layers 1,2: pull bf16 emb rows at batch indices into fp32 accs.
__global__ void gather_acc_kernel(const int* __restrict__ users,
                                  const int* __restrict__ items,
                                  const unsigned* __restrict__ emb,  // bf16x2
                                  float* __restrict__ u_acc,
                                  float* __restrict__ i_acc) {
    int gid = blockIdx.x * blockDim.x + threadIdx.x;  // 2*BATCH*32 threads
    int ui = gid & 31;
    int b  = gid >> 5;
    if (b < BATCH) {
        unsigned p = emb[(size_t)users[b] * 32 + ui];
        u_acc[(size_t)b * D + 2 * ui]     += bf16_lo(p);
        u_acc[(size_t)b * D + 2 * ui + 1] += bf16_hi(p);
    } else if (b < 2 * BATCH) {
        int bb = b - BATCH;
        unsigned p = emb[((size_t)(N_USERS + items[bb])) * 32 + ui];
        i_acc[(size_t)bb * D + 2 * ui]     += bf16_lo(p);
        i_acc[(size_t)bb * D + 2 * ui + 1] += bf16_hi(p);
    }
}

__global__ void final_dot_kernel(const float* __restrict__ u_acc,
                                 const float* __restrict__ i_acc,
                                 float* __restrict__ out) {
    int gid = blockIdx.x * blockDim.x + threadIdx.x;
    int b = gid >> 6;
    int lane = gid & 63;
    if (b >= BATCH) return;
    float p = u_acc[(size_t)b * D + lane] * i_acc[(size_t)b * D + lane];
#pragma unroll
    for (int o = 32; o; o >>= 1) p += __shfl_xor(p, o, 64);
    if (lane == 0) out[b] = p * (1.0f / 16.0f);
}

// ---------------- launch ----------------

extern "C" void kernel_launch(void* const* d_in, const int* in_sizes, int n_in,
                              void* d_out, int out_size, void* d_ws, size_t ws_size,
                              hipStream_t stream) {
    const int*   users = (const int*)d_in[0];
    const int*   items = (const int*)d_in[1];
    const float* ue    = (const float*)d_in[2];
    const float* ie    = (const float*)d_in[3];
    const int*   rows  = (const int*)d_in[4];
    const int*   cols  = (const int*)d_in[5];
    const float* vals  = (const float*)d_in[6];
    float*       out   = (float*)d_out;

    char* ws = (char*)d_ws;
    size_t off = 0;
    auto alloc = [&](size_t bytes) {
        void* p = ws + off;
        off += (bytes + 255) & ~(size_t)255;
        return p;
    };
    const size_t NBH = (size_t)N_TOTAL * D * sizeof(unsigned short);  // 19.2 MB bf16
    char*  embA      = (char*)alloc(NBH);
    char*  embB      = (char*)alloc(NBH);
    float* u_acc     = (float*)alloc((size_t)BATCH * D * sizeof(float));
    float* i_acc     = (float*)alloc((size_t)BATCH * D * sizeof(float));
    int*   row_start = (int*)alloc(((size_t)N_TOTAL + 1) * sizeof(int));
    int*   bucketcnt = (int*)alloc((size_t)NBUCKETS * sizeof(int));
    int*   bucketoff = (int*)alloc(((size_t)NBUCKETS + 1) * sizeof(int));
    int*   cursor    = (int*)alloc((size_t)NBUCKETS * sizeof(int));
    int2*  edges     = (int2*)alloc((size_t)NNZ * sizeof(int2));
    int2*  bucketed  = (int2*)alloc((size_t)NNZ * sizeof(int2));

    // init
    {
        size_t tot4 = (size_t)N_TOTAL * D / 4;
        init_emb_kernel<<<(unsigned)((tot4 + 255) / 256), 256, 0, stream>>>(
            (const float4*)ue, (const float4*)ie, (uint2*)embA);
        init_acc_kernel<<<(2 * BATCH * D + 255) / 256, 256, 0, stream>>>(
            users, items, ue, ie, u_acc, i_acc);
    }

    // CSR build (two-level bucketing, LDS-staged coalesced scatter)
    hipMemsetAsync(bucketcnt, 0, (size_t)NBUCKETS * sizeof(int), stream);
    bucket_hist_kernel<<<512, 256, 0, stream>>>(rows, bucketcnt);
    bucket_scan_kernel<<<1, 1024, 0, stream>>>(bucketcnt, bucketoff, cursor);
    bucket_scatter_kernel<<<SCAT_BLOCKS, SCAT_THREADS, 0, stream>>>(
        rows, cols, vals, cursor, bucketed);
    local_sort_kernel<<<NBUCKETS, LS_THREADS, 0, stream>>>(
        bucketoff, bucketed, row_start, edges);

    // Layer 1: embA -> embB
    spmm_csr_kernel<<<(N_TOTAL * 64 + 255) / 256, 256, 0, stream>>>(
        row_start, edges, embA, (uint2*)embB);
    gather_acc_kernel<<<(2 * BATCH * 32 + 255) / 256, 256, 0, stream>>>(
        users, items, (const unsigned*)embB, u_acc, i_acc);

    // Layer 2: embB -> embA
    spmm_csr_kernel<<<(N_TOTAL * 64 + 255) / 256, 256, 0, stream>>>(
        row_start, edges, embB, (uint2*)embA);
    gather_acc_kernel<<<(2 * BATCH * 32 + 255) / 256, 256, 0, stream>>>(
        users, items, (const unsigned*)embA, u_acc, i_acc);

    // Layer 3: only the 8192 batch rows, straight into accs
    layer3_kernel<<<(2 * BATCH * 64 + 255) / 256, 256, 0, stream>>>(
        users, items, row_start, edges, embA, u_acc, i_acc);

    final_dot_kernel<<<(BATCH * 64 + 255) / 256, 256, 0, stream>>>(u_acc, i_acc, out);
}

// Round 14
// 348.240 us; speedup vs baseline: 2.2389x; 1.0744x over previous
//
#include <hip/hip_runtime.h>

#define N_USERS 100000
#define M_ITEMS 50000
#define N_TOTAL (N_USERS + M_ITEMS)
#define D 64
#define NNZ 4000000
#define BATCH 4096

#define RPB 128                                   // rows per bucket (pow2)
#define BSHIFT 7
#define NBUCKETS ((N_TOTAL + RPB - 1) / RPB)      // 1172
#define BCAP 7680                                 // LDS edge capacity per bucket

#define TILE 8192                                 // edges per scatter block
#define SCAT_BLOCKS ((NNZ + TILE - 1) / TILE)     // 489
#define SCAT_THREADS 1024
#define EPT (TILE / SCAT_THREADS)                 // 8 edges per thread
#define CPB 2                                     // buckets per thread in block scan (1024*2>=1172)

#define LS_THREADS 1024
#define LS_EPT 8

// ---- bf16 helpers (RNE) ----
__device__ __forceinline__ unsigned pack_bf16(float a, float b) {
    unsigned ua = __float_as_uint(a);
    unsigned ub = __float_as_uint(b);
    ua = (ua + 0x7FFFu + ((ua >> 16) & 1u)) >> 16;
    ub = (ub + 0x7FFFu + ((ub >> 16) & 1u)) & 0xFFFF0000u;
    return ua | ub;
}
__device__ __forceinline__ float bf16_lo(unsigned p) { return __uint_as_float(p << 16); }
__device__ __forceinline__ float bf16_hi(unsigned p) { return __uint_as_float(p & 0xFFFF0000u); }

// ---------------- init ----------------

// Concatenate + convert fp32 embeddings to packed bf16 (2 dims per uint).
__global__ void init_emb_kernel(const float4* __restrict__ ue,
                                const float4* __restrict__ ie,
                                uint2* __restrict__ emb) {
    size_t i = (size_t)blockIdx.x * blockDim.x + threadIdx.x;  // one float4 -> uint2
    const size_t nu4  = (size_t)N_USERS * D / 4;
    const size_t tot4 = (size_t)N_TOTAL * D / 4;
    if (i >= tot4) return;
    float4 f = (i < nu4) ? ue[i] : ie[i - nu4];
    emb[i] = make_uint2(pack_bf16(f.x, f.y), pack_bf16(f.z, f.w));
}

__global__ void init_acc_kernel(const int* __restrict__ users,
                                const int* __restrict__ items,
                                const float* __restrict__ ue,
                                const float* __restrict__ ie,
                                float* __restrict__ u_acc,
                                float* __restrict__ i_acc) {
    int gid = blockIdx.x * blockDim.x + threadIdx.x;  // 2*BATCH*D threads
    int d = gid & (D - 1);
    int b = gid >> 6;
    if (b < BATCH) {
        u_acc[(size_t)b * D + d] = ue[(size_t)users[b] * D + d];
    } else if (b < 2 * BATCH) {
        int bb = b - BATCH;
        i_acc[(size_t)bb * D + d] = ie[(size_t)items[bb] * D + d];
    }
}

// ---------------- CSR build: two-level bucketing ----------------

__global__ void bucket_hist_kernel(const int* __restrict__ rows,
                                   int* __restrict__ bucketcnt) {
    __shared__ int h[NBUCKETS];
    for (int i = threadIdx.x; i < NBUCKETS; i += blockDim.x) h[i] = 0;
    __syncthreads();
    int stride = gridDim.x * blockDim.x;
    for (int e = blockIdx.x * blockDim.x + threadIdx.x; e < NNZ; e += stride)
        atomicAdd(&h[rows[e] >> BSHIFT], 1);
    __syncthreads();
    for (int i = threadIdx.x; i < NBUCKETS; i += blockDim.x)
        if (h[i]) atomicAdd(&bucketcnt[i], h[i]);
}

__global__ void bucket_scan_kernel(const int* __restrict__ cnt,
                                   int* __restrict__ bucketoff,
                                   int* __restrict__ cursor) {
    __shared__ int sc[1024];
    int t = threadIdx.x;
    int i0 = t * 2, i1 = t * 2 + 1;
    int a = (i0 < NBUCKETS) ? cnt[i0] : 0;
    int b = (i1 < NBUCKETS) ? cnt[i1] : 0;
    sc[t] = a + b;
    __syncthreads();
    for (int o = 1; o < 1024; o <<= 1) {
        int v = (t >= o) ? sc[t - o] : 0;
        __syncthreads();
        sc[t] += v;
        __syncthreads();
    }
    int excl = (t == 0) ? 0 : sc[t - 1];
    if (i0 < NBUCKETS) { bucketoff[i0] = excl;     cursor[i0] = excl; }
    if (i1 < NBUCKETS) { bucketoff[i1] = excl + a; cursor[i1] = excl + a; }
    if (t == 0) bucketoff[NBUCKETS] = NNZ;
}

// Tile-aggregated scatter with LDS staging; lane-parallel coalesced stream-out.
// 1024 threads: 16 waves per (single-occupancy) block for latency hiding.
__global__ __launch_bounds__(SCAT_THREADS)
void bucket_scatter_kernel(const int* __restrict__ rows,
                           const int* __restrict__ cols,
                           const float* __restrict__ vals,
                           int* __restrict__ cursor,
                           int2* __restrict__ bucketed) {
    __shared__ int hist[NBUCKETS];        // counts, then global base per bucket
    __shared__ int loff[NBUCKETS + 1];    // local exclusive prefix
    __shared__ int partial[SCAT_THREADS];
    __shared__ int2 buf[TILE];            // 64 KB
    __shared__ int dst[TILE];             // 32 KB
    int t = threadIdx.x;
    size_t start = (size_t)blockIdx.x * TILE;
    int n = (int)(((size_t)NNZ - start < TILE) ? ((size_t)NNZ - start) : TILE);

    for (int i = t; i < NBUCKETS; i += SCAT_THREADS) hist[i] = 0;
    __syncthreads();
    // Phase A: histogram; atomicAdd's return IS the local rank.
    int rowv[EPT];
    int rank[EPT];
#pragma unroll
    for (int k = 0; k < EPT; ++k) {
        int i = t + k * SCAT_THREADS;
        if (i < n) {
            int r = rows[start + i];
            rowv[k] = r;
            rank[k] = atomicAdd(&hist[r >> BSHIFT], 1);
        }
    }
    __syncthreads();
    // Phase B1: block scan hist -> loff (exclusive)
    {
        int base = t * CPB;
        int s = 0;
#pragma unroll
        for (int j = 0; j < CPB; ++j) {
            int idx = base + j;
            if (idx < NBUCKETS) s += hist[idx];
        }
        partial[t] = s;
        __syncthreads();
        for (int o = 1; o < SCAT_THREADS; o <<= 1) {
            int v = (t >= o) ? partial[t - o] : 0;
            __syncthreads();
            partial[t] += v;
            __syncthreads();
        }
        int excl = (t == 0) ? 0 : partial[t - 1];
#pragma unroll
        for (int j = 0; j < CPB; ++j) {
            int idx = base + j;
            if (idx < NBUCKETS) { loff[idx] = excl; excl += hist[idx]; }
        }
        if (t == 0) loff[NBUCKETS] = n;
    }
    __syncthreads();
    // Phase B2: one global reservation per touched bucket; hist becomes gbase.
    for (int i = t; i < NBUCKETS; i += SCAT_THREADS) {
        int c = loff[i + 1] - loff[i];
        hist[i] = c ? atomicAdd(&cursor[i], c) : 0;
    }
    __syncthreads();
    // Phase C: place edges bucket-sorted in LDS; record global dest per slot.
#pragma unroll
    for (int k = 0; k < EPT; ++k) {
        int i = t + k * SCAT_THREADS;
        if (i < n) {
            int r = rowv[k];
            int bkt = r >> BSHIFT;
            int slot = loff[bkt] + rank[k];
            buf[slot] = make_int2(((r & (RPB - 1)) << 18) | cols[start + i],
                                  __float_as_int(vals[start + i]));
            dst[slot] = hist[bkt] + rank[k];
        }
    }
    __syncthreads();
    // Phase D: lane-parallel coalesced stream-out.
    for (int i = t; i < n; i += SCAT_THREADS)
        bucketed[dst[i]] = buf[i];
}

// Per-bucket counting sort in LDS (rank fused, payload held in registers).
// Output edge format: x = col byte offset (col*128), y = f32 val.
__global__ __launch_bounds__(LS_THREADS)
void local_sort_kernel(const int* __restrict__ bucketoff,
                       const int2* __restrict__ bucketed,
                       int* __restrict__ row_start,
                       int2* __restrict__ edges) {
    __shared__ int hist[RPB];
    __shared__ int sc[RPB];
    __shared__ int2 buf[BCAP];
    int b = blockIdx.x;
    int t = threadIdx.x;
    int s = bucketoff[b], e = bucketoff[b + 1], n = e - s;

    if (t < RPB) hist[t] = 0;
    __syncthreads();
    int rl[LS_EPT], rank[LS_EPT];
    int2 pay[LS_EPT];
#pragma unroll
    for (int k = 0; k < LS_EPT; ++k) {
        int i = t + k * LS_THREADS;
        if (i < n) {
            int2 ev = bucketed[s + i];
            rl[k] = (int)((unsigned)ev.x >> 18);
            pay[k] = make_int2((ev.x & 0x3FFFF) << 7, ev.y);
            rank[k] = atomicAdd(&hist[rl[k]], 1);
        }
    }
    __syncthreads();
    if (t < RPB) sc[t] = hist[t];
    __syncthreads();
    for (int o = 1; o < RPB; o <<= 1) {
        int v = (t < RPB && t >= o) ? sc[t - o] : 0;
        __syncthreads();
        if (t < RPB) sc[t] += v;
        __syncthreads();
    }
    if (t < RPB) {
        int excl = (t == 0) ? 0 : sc[t - 1];
        int gr = b * RPB + t;
        if (gr < N_TOTAL) row_start[gr] = s + excl;
    }
    if (b == 0 && t == 0) row_start[N_TOTAL] = NNZ;
    __syncthreads();
#pragma unroll
    for (int k = 0; k < LS_EPT; ++k) {
        int i = t + k * LS_THREADS;
        if (i < n) {
            int excl = (rl[k] == 0) ? 0 : sc[rl[k] - 1];
            int p = excl + rank[k];
            if (p < BCAP) buf[p] = pay[k];
            else          edges[s + p] = pay[k];
        }
    }
    __syncthreads();
    int m = (n < BCAP) ? n : BCAP;
    for (int i = t; i < m; i += LS_THREADS) edges[s + i] = buf[i];
}

// ---------------- bf16 CSR SpMM, oct-split, unroll-4 MLP ----------------
// One wave per row. oct = lane>>3 processes edges 8t+oct; ui = lane&7
// covers dims 8ui..8ui+7 via one uint4 load (8 lanes x 16 B = 128 B/edge).
// Unrolled x4: 4 x 16 B gathers in flight per lane.
__global__ void spmm_csr_kernel(const int* __restrict__ row_start,
                                const int2* __restrict__ edges,   // x = col*128
                                const char* __restrict__ emb_in,  // bf16 rows, 128 B
                                uint4* __restrict__ emb_out) {
    int wave = (blockIdx.x * blockDim.x + threadIdx.x) >> 6;
    int lane = threadIdx.x & 63;
    if (wave >= N_TOTAL) return;
    int oct = lane >> 3;
    int ui  = lane & 7;
    int uioff = ui << 4;
    int s = row_start[wave];
    int e = row_start[wave + 1];
    float a0 = 0.f, a1 = 0.f, a2 = 0.f, a3 = 0.f;
    float a4 = 0.f, a5 = 0.f, a6 = 0.f, a7 = 0.f;
    for (int base = s; base < e; base += 64) {
        int n = e - base; if (n > 64) n = 64;
        int c = 0; float v = 0.0f;
        if (base + lane < e) {
            int2 ev = edges[base + lane];
            c = ev.x; v = __int_as_float(ev.y);
        }
        int tmax = (n + 7) >> 3;
        int t = 0;
        for (; t + 4 <= tmax; t += 4) {
            int j0 = 8 * t + oct, j1 = j0 + 8, j2 = j0 + 16, j3 = j0 + 24;
            int   c0 = __shfl(c, j0, 64), c1 = __shfl(c, j1, 64);
            int   c2 = __shfl(c, j2, 64), c3 = __shfl(c, j3, 64);
            float v0 = __shfl(v, j0, 64), v1 = __shfl(v, j1, 64);
            float v2 = __shfl(v, j2, 64), v3 = __shfl(v, j3, 64);
            uint4 p0 = *(const uint4*)(emb_in + c0 + uioff);
            uint4 p1 = *(const uint4*)(emb_in + c1 + uioff);
            uint4 p2 = *(const uint4*)(emb_in + c2 + uioff);
            uint4 p3 = *(const uint4*)(emb_in + c3 + uioff);
            float m0 = (j0 < n) ? v0 : 0.0f;
            float m1 = (j1 < n) ? v1 : 0.0f;
            float m2 = (j2 < n) ? v2 : 0.0f;
            float m3 = (j3 < n) ? v3 : 0.0f;
            a0 += m0 * bf16_lo(p0.x); a1 += m0 * bf16_hi(p0.x);
            a2 += m0 * bf16_lo(p0.y); a3 += m0 * bf16_hi(p0.y);
            a4 += m0 * bf16_lo(p0.z); a5 += m0 * bf16_hi(p0.z);
            a6 += m0 * bf16_lo(p0.w); a7 += m0 * bf16_hi(p0.w);
            a0 += m1 * bf16_lo(p1.x); a1 += m1 * bf16_hi(p1.x);
            a2 += m1 * bf16_lo(p1.y); a3 += m1 * bf16_hi(p1.y);
            a4 += m1 * bf16_lo(p1.z); a5 += m1 * bf16_hi(p1.z);
            a6 += m1 * bf16_lo(p1.w); a7 += m1 * bf16_hi(p1.w);
            a0 += m2 * bf16_lo(p2.x); a1 += m2 * bf16_hi(p2.x);
            a2 += m2 * bf16_lo(p2.y); a3 += m2 * bf16_hi(p2.y);
            a4 += m2 * bf16_lo(p2.z); a5 += m2 * bf16_hi(p2.z);
            a6 += m2 * bf16_lo(p2.w); a7 += m2 * bf16_hi(p2.w);
            a0 += m3 * bf16_lo(p3.x); a1 += m3 * bf16_hi(p3.x);
            a2 += m3 * bf16_lo(p3.y); a3 += m3 * bf16_hi(p3.y);
            a4 += m3 * bf16_lo(p3.z); a5 += m3 * bf16_hi(p3.z);
            a6 += m3 * bf16_lo(p3.w); a7 += m3 * bf16_hi(p3.w);
        }
        for (; t < tmax; ++t) {
            int j = 8 * t + oct;
            int   cj = __shfl(c, j, 64);
            float vj = __shfl(v, j, 64);
            float m  = (j < n) ? vj : 0.0f;
            uint4 p = *(const uint4*)(emb_in + cj + uioff);
            a0 += m * bf16_lo(p.x); a1 += m * bf16_hi(p.x);
            a2 += m * bf16_lo(p.y); a3 += m * bf16_hi(p.y);
            a4 += m * bf16_lo(p.z); a5 += m * bf16_hi(p.z);
            a6 += m * bf16_lo(p.w); a7 += m * bf16_hi(p.w);
        }
    }
#pragma unroll
    for (int o = 8; o <= 32; o <<= 1) {
        a0 += __shfl_xor(a0, o, 64); a1 += __shfl_xor(a1, o, 64);
        a2 += __shfl_xor(a2, o, 64); a3 += __shfl_xor(a3, o, 64);
        a4 += __shfl_xor(a4, o, 64); a5 += __shfl_xor(a5, o, 64);
        a6 += __shfl_xor(a6, o, 64); a7 += __shfl_xor(a7, o, 64);
    }
    if (oct == 0)
        emb_out[(size_t)wave * 8 + ui] =
            make_uint4(pack_bf16(a0, a1), pack_bf16(a2, a3),
                       pack_bf16(a4, a5), pack_bf16(a6, a7));
}

// Layer-3: segment sums ONLY for the 8192 batch rows, added into fp32 accs.
__global__ void layer3_kernel(const int* __restrict__ users,
                              const int* __restrict__ items,
                              const int* __restrict__ row_start,
                              const int2* __restrict__ edges,
                              const char* __restrict__ emb_in,  // bf16 rows
                              float* __restrict__ u_acc,
                              float* __restrict__ i_acc) {
    int wave = (blockIdx.x * blockDim.x + threadIdx.x) >> 6;
    int lane = threadIdx.x & 63;
    if (wave >= 2 * BATCH) return;
    int oct = lane >> 3;
    int ui  = lane & 7;
    int uioff = ui << 4;
    int row;
    float* dstp;
    if (wave < BATCH) {
        row = users[wave];
        dstp = &u_acc[(size_t)wave * D];
    } else {
        int bb = wave - BATCH;
        row = N_USERS + items[bb];
        dstp = &i_acc[(size_t)bb * D];
    }
    int s = row_start[row];
    int e = row_start[row + 1];
    float a0 = 0.f, a1 = 0.f, a2 = 0.f, a3 = 0.f;
    float a4 = 0.f, a5 = 0.f, a6 = 0.f, a7 = 0.f;
    for (int base = s; base < e; base += 64) {
        int n = e - base; if (n > 64) n = 64;
        int c = 0; float v = 0.0f;
        if (base + lane < e) {
            int2 ev = edges[base + lane];
            c = ev.x; v = __int_as_float(ev.y);
        }
        int tmax = (n + 7) >> 3;
        int t = 0;
        for (; t + 4 <= tmax; t += 4) {
            int j0 = 8 * t + oct, j1 = j0 + 8, j2 = j0 + 16, j3 = j0 + 24;
            int   c0 = __shfl(c, j0, 64), c1 = __shfl(c, j1, 64);
            int   c2 = __shfl(c, j2, 64), c3 = __shfl(c, j3, 64);
            float v0 = __shfl(v, j0, 64), v1 = __shfl(v, j1, 64);
            float v2 = __shfl(v, j2, 64), v3 = __shfl(v, j3, 64);
            uint4 p0 = *(const uint4*)(emb_in + c0 + uioff);
            uint4 p1 = *(const uint4*)(emb_in + c1 + uioff);
            uint4 p2 = *(const uint4*)(emb_in + c2 + uioff);
            uint4 p3 = *(const uint4*)(emb_in + c3 + uioff);
            float m0 = (j0 < n) ? v0 : 0.0f;
            float m1 = (j1 < n) ? v1 : 0.0f;
            float m2 = (j2 < n) ? v2 : 0.0f;
            float m3 = (j3 < n) ? v3 : 0.0f;
            a0 += m0 * bf16_lo(p0.x); a1 += m0 * bf16_hi(p0.x);
            a2 += m0 * bf16_lo(p0.y); a3 += m0 * bf16_hi(p0.y);
            a4 += m0 * bf16_lo(p0.z); a5 += m0 * bf16_hi(p0.z);
            a6 += m0 * bf16_lo(p0.w); a7 += m0 * bf16_hi(p0.w);
            a0 += m1 * bf16_lo(p1.x); a1 += m1 * bf16_hi(p1.x);
            a2 += m1 * bf16_lo(p1.y); a3 += m1 * bf16_hi(p1.y);
            a4 += m1 * bf16_lo(p1.z); a5 += m1 * bf16_hi(p1.z);
            a6 += m1 * bf16_lo(p1.w); a7 += m1 * bf16_hi(p1.w);
            a0 += m2 * bf16_lo(p2.x); a1 += m2 * bf16_hi(p2.x);
            a2 += m2 * bf16_lo(p2.y); a3 += m2 * bf16_hi(p2.y);
            a4 += m2 * bf16_lo(p2.z); a5 += m2 * bf16_hi(p2.z);
            a6 += m2 * bf16_lo(p2.w); a7 += m2 * bf16_hi(p2.w);
            a0 += m3 * bf16_lo(p3.x); a1 += m3 * bf16_hi(p3.x);
            a2 += m3 * bf16_lo(p3.y); a3 += m3 * bf16_hi(p3.y);
            a4 += m3 * bf16_lo(p3.z); a5 += m3 * bf16_hi(p3.z);
            a6 += m3 * bf16_lo(p3.w); a7 += m3 * bf16_hi(p3.w);
        }
        for (; t < tmax; ++t) {
            int j = 8 * t + oct;
            int   cj = __shfl(c, j, 64);
            float vj = __shfl(v, j, 64);
            float m  = (j < n) ? vj : 0.0f;
            uint4 p = *(const uint4*)(emb_in + cj + uioff);
            a0 += m * bf16_lo(p.x); a1 += m * bf16_hi(p.x);
            a2 += m * bf16_lo(p.y); a3 += m * bf16_hi(p.y);
            a4 += m * bf16_lo(p.z); a5 += m * bf16_hi(p.z);
            a6 += m * bf16_lo(p.w); a7 += m * bf16_hi(p.w);
        }
    }
#pragma unroll
    for (int o = 8; o <= 32; o <<= 1) {
        a0 += __shfl_xor(a0, o, 64); a1 += __shfl_xor(a1, o, 64);
        a2 += __shfl_xor(a2, o, 64); a3 += __shfl_xor(a3, o, 64);
        a4 += __shfl_xor(a4, o, 64); a5 += __shfl_xor(a5, o, 64);
        a6 += __shfl_xor(a6, o, 64); a7 += __shfl_xor(a7, o, 64);
    }
    if (oct == 0) {
        dstp[8 * ui + 0] += a0; dstp[8 * ui + 1] += a1;
        dstp[8 * ui + 2] += a2; dstp[8 * ui + 3] += a3;
        dstp[8 * ui + 4] += a4; dstp[8 * ui + 5] += a5;
        dstp[8 * ui + 6] += a6; dstp[8 * ui + 7] += a7;
    }
}

// After layers 1,2: pull bf16 emb rows at batch indices into fp32 accs.
__global__ void gather_acc_kernel(const int* __restrict__ users,
                                  const int* __restrict__ items,
                                  const unsigned* __restrict__ emb,  // bf16x2
                                  float* __restrict__ u_acc,
                                  float* __restrict__ i_acc) {
    int gid = blockIdx.x * blockDim.x + threadIdx.x;  // 2*BATCH*32 threads
    int ui = gid & 31;
    int b  = gid >> 5;
    if (b < BATCH) {
        unsigned p = emb[(size_t)users[b] * 32 + ui];
        u_acc[(size_t)b * D + 2 * ui]     += bf16_lo(p);
        u_acc[(size_t)b * D + 2 * ui + 1] += bf16_hi(p);
    } else if (b < 2 * BATCH) {
        int bb = b - BATCH;
        unsigned p = emb[((size_t)(N_USERS + items[bb])) * 32 + ui];
        i_acc[(size_t)bb * D + 2 * ui]     += bf16_lo(p);
        i_acc[(size_t)bb * D + 2 * ui + 1] += bf16_hi(p);
    }
}

__global__ void final_dot_kernel(const float* __restrict__ u_acc,
                                 const float* __restrict__ i_acc,
                                 float* __restrict__ out) {
    int gid = blockIdx.x * blockDim.x + threadIdx.x;
    int b = gid >> 6;
    int lane = gid & 63;
    if (b >= BATCH) return;
    float p = u_acc[(size_t)b * D + lane] * i_acc[(size_t)b * D + lane];
#pragma unroll
    for (int o = 32; o; o >>= 1) p += __shfl_xor(p, o, 64);
    if (lane == 0) out[b] = p * (1.0f / 16.0f);
}

// ---------------- launch ----------------

extern "C" void kernel_launch(void* const* d_in, const int* in_sizes, int n_in,
                              void* d_out, int out_size, void* d_ws, size_t ws_size,
                              hipStream_t stream) {
    const int*   users = (const int*)d_in[0];
    const int*   items = (const int*)d_in[1];
    const float* ue    = (const float*)d_in[2];
    const float* ie    = (const float*)d_in[3];
    const int*   rows  = (const int*)d_in[4];
    const int*   cols  = (const int*)d_in[5];
    const float* vals  = (const float*)d_in[6];
    float*       out   = (float*)d_out;

    char* ws = (char*)d_ws;
    size_t off = 0;
    auto alloc = [&](size_t bytes) {
        void* p = ws + off;
        off += (bytes + 255) & ~(size_t)255;
        return p;
    };
    const size_t NBH = (size_t)N_TOTAL * D * sizeof(unsigned short);  // 19.2 MB bf16
    char*  embA      = (char*)alloc(NBH);
    char*  embB      = (char*)alloc(NBH);
    float* u_acc     = (float*)alloc((size_t)BATCH * D * sizeof(float));
    float* i_acc     = (float*)alloc((size_t)BATCH * D * sizeof(float));
    int*   row_start = (int*)alloc(((size_t)N_TOTAL + 1) * sizeof(int));
    int*   bucketcnt = (int*)alloc((size_t)NBUCKETS * sizeof(int));
    int*   bucketoff = (int*)alloc(((size_t)NBUCKETS + 1) * sizeof(int));
    int*   cursor    = (int*)alloc((size_t)NBUCKETS * sizeof(int));
    int2*  edges     = (int2*)alloc((size_t)NNZ * sizeof(int2));
    int2*  bucketed  = (int2*)alloc((size_t)NNZ * sizeof(int2));

    // init
    {
        size_t tot4 = (size_t)N_TOTAL * D / 4;
        init_emb_kernel<<<(unsigned)((tot4 + 255) / 256), 256, 0, stream>>>(
            (const float4*)ue, (const float4*)ie, (uint2*)embA);
        init_acc_kernel<<<(2 * BATCH * D + 255) / 256, 256, 0, stream>>>(
            users, items, ue, ie, u_acc, i_acc);
    }

    // CSR build (two-level bucketing, LDS-staged coalesced scatter)
    hipMemsetAsync(bucketcnt, 0, (size_t)NBUCKETS * sizeof(int), stream);
    bucket_hist_kernel<<<512, 256, 0, stream>>>(rows, bucketcnt);
    bucket_scan_kernel<<<1, 1024, 0, stream>>>(bucketcnt, bucketoff, cursor);
    bucket_scatter_kernel<<<SCAT_BLOCKS, SCAT_THREADS, 0, stream>>>(
        rows, cols, vals, cursor, bucketed);
    local_sort_kernel<<<NBUCKETS, LS_THREADS, 0, stream>>>(
        bucketoff, bucketed, row_start, edges);

    // Layer 1: embA -> embB
    spmm_csr_kernel<<<(N_TOTAL * 64 + 255) / 256, 256, 0, stream>>>(
        row_start, edges, embA, (uint4*)embB);
    gather_acc_kernel<<<(2 * BATCH * 32 + 255) / 256, 256, 0, stream>>>(
        users, items, (const unsigned*)embB, u_acc, i_acc);

    // Layer 2: embB -> embA
    spmm_csr_kernel<<<(N_TOTAL * 64 + 255) / 256, 256, 0, stream>>>(
        row_start, edges, embB, (uint4*)embA);
    gather_acc_kernel<<<(2 * BATCH * 32 + 255) / 256, 256, 0, stream>>>(
        users, items, (const unsigned*)embA, u_acc, i_acc);

    // Layer 3: only the 8192 batch rows, straight into accs
    layer3_kernel<<<(2 * BATCH * 64 + 255) / 256, 256, 0, stream>>>(
        users, items, row_start, edges, embA, u_acc, i_acc);

    final_dot_kernel<<<(BATCH * 64 + 255) / 256, 256, 0, stream>>>(u_acc, i_acc, out);
}